// Round 6
// baseline (558.761 us; speedup 1.0000x reference)
//
#include <hip/hip_runtime.h>
#include <math.h>

// Problem constants (match reference)
#define NN 50000
#define NE 800000
#define DIN 256
#define HH 128      // H1 == H2 == 128
#define DOUT 40
#define NN_PAD 50176   // NN rounded to 256

// ---------------------------------------------------------------------------
// CSR build step 1: in-degree count (self-loop handled as +1 later)
__global__ __launch_bounds__(256) void k_cnt(const int* __restrict__ dst,
                                             int* __restrict__ cnt) {
    int e = blockIdx.x * 256 + threadIdx.x;
    if (e < NE) atomicAdd(&cnt[dst[e]], 1);
}

// CSR build step 2a: per-256-block inclusive scan + block sums; fused dinv
__global__ __launch_bounds__(256) void scan_part(const int* __restrict__ cnt,
                                                 int* __restrict__ incl,
                                                 int* __restrict__ bsum,
                                                 float* __restrict__ dinv) {
    __shared__ int s[256];
    int t = threadIdx.x;
    int id = blockIdx.x * 256 + t;
    int c = cnt[id];                   // cnt padded to NN_PAD, pad = 0
    dinv[id] = rsqrtf((float)c + 1.0f);
    s[t] = c;
    __syncthreads();
    #pragma unroll
    for (int off = 1; off < 256; off <<= 1) {
        int v = (t >= off) ? s[t - off] : 0;
        __syncthreads();
        s[t] += v;
        __syncthreads();
    }
    incl[id] = s[t];
    if (t == 255) bsum[blockIdx.x] = s[255];
}

// CSR build step 2b: exclusive scan of block sums (single block, nb<=256)
__global__ __launch_bounds__(256) void scan_bsum(int* __restrict__ bsum, int nb) {
    __shared__ int s[256];
    int t = threadIdx.x;
    int orig = (t < nb) ? bsum[t] : 0;
    s[t] = orig;
    __syncthreads();
    #pragma unroll
    for (int off = 1; off < 256; off <<= 1) {
        int v = (t >= off) ? s[t - off] : 0;
        __syncthreads();
        s[t] += v;
        __syncthreads();
    }
    if (t < nb) bsum[t] = s[t] - orig;   // exclusive
}

// CSR build step 2c: global exclusive rowptr
__global__ __launch_bounds__(256) void scan_final(const int* __restrict__ incl,
                                                  const int* __restrict__ cnt,
                                                  const int* __restrict__ bsum,
                                                  int* __restrict__ rowptr) {
    int id = blockIdx.x * 256 + threadIdx.x;
    if (id < NN) rowptr[id] = incl[id] - cnt[id] + bsum[id >> 8];
    if (id == 0) rowptr[NN] = NE;
}

// CSR build step 3: fill (src index + precomputed edge norm)
__global__ __launch_bounds__(256) void fill_csr(
    const int* __restrict__ src, const int* __restrict__ dst,
    const float* __restrict__ dinv, const int* __restrict__ rowptr,
    int* __restrict__ cursor, int* __restrict__ csr_src,
    float* __restrict__ csr_norm) {
    int e = blockIdx.x * 256 + threadIdx.x;
    if (e >= NE) return;
    int s = src[e], d = dst[e];
    int pos = rowptr[d] + atomicAdd(&cursor[d], 1);
    csr_src[pos] = s;
    csr_norm[pos] = dinv[s] * dinv[d];
}

// ---------------------------------------------------------------------------
// Gather aggregation: out[d] = sum_{e: dst=d} h[src]*norm + h[d]*dinv[d]^2
//   (+ bias) (+ optional relu).
// ONE NODE PER WAVE (64 lanes x float2): node index is wave-uniform ->
// rowptr/csr_src/csr_norm compile to scalar s_loads (SMEM pipe), leaving
// VMEM purely for the 512B coalesced row gathers. 4x unrolled for MLP.
__global__ __launch_bounds__(256) void gather_csr(
    const int* __restrict__ rowptr, const int* __restrict__ csr_src,
    const float* __restrict__ csr_norm, const float* __restrict__ dinv,
    const float* __restrict__ h, const float* __restrict__ bias,
    float* __restrict__ out, int relu) {
    int node = blockIdx.x * 4 + (threadIdx.x >> 6);   // 12500 blocks x 4 waves
    node = __builtin_amdgcn_readfirstlane(node);      // force SGPR (uniform)
    int lane = threadIdx.x & 63;
    float dd = dinv[node];
    float sl = dd * dd;                               // self-loop norm
    const float2 hv = *reinterpret_cast<const float2*>(&h[(long)node * HH + lane * 2]);
    float2 acc = make_float2(hv.x * sl, hv.y * sl);
    int beg = rowptr[node], end = rowptr[node + 1];
    int i = beg;
    for (; i + 4 <= end; i += 4) {
        int s0 = csr_src[i],     s1 = csr_src[i + 1];
        int s2 = csr_src[i + 2], s3 = csr_src[i + 3];
        float n0 = csr_norm[i],     n1 = csr_norm[i + 1];
        float n2 = csr_norm[i + 2], n3 = csr_norm[i + 3];
        const float2 v0 = *reinterpret_cast<const float2*>(&h[(long)s0 * HH + lane * 2]);
        const float2 v1 = *reinterpret_cast<const float2*>(&h[(long)s1 * HH + lane * 2]);
        const float2 v2 = *reinterpret_cast<const float2*>(&h[(long)s2 * HH + lane * 2]);
        const float2 v3 = *reinterpret_cast<const float2*>(&h[(long)s3 * HH + lane * 2]);
        acc.x += v0.x * n0; acc.y += v0.y * n0;
        acc.x += v1.x * n1; acc.y += v1.y * n1;
        acc.x += v2.x * n2; acc.y += v2.y * n2;
        acc.x += v3.x * n3; acc.y += v3.y * n3;
    }
    for (; i < end; i++) {
        int s0 = csr_src[i];
        float n0 = csr_norm[i];
        const float2 v0 = *reinterpret_cast<const float2*>(&h[(long)s0 * HH + lane * 2]);
        acc.x += v0.x * n0; acc.y += v0.y * n0;
    }
    const float2 bv = *reinterpret_cast<const float2*>(&bias[lane * 2]);
    acc.x += bv.x; acc.y += bv.y;
    if (relu) { acc.x = fmaxf(acc.x, 0.f); acc.y = fmaxf(acc.y, 0.f); }
    *reinterpret_cast<float2*>(&out[(long)node * HH + lane * 2]) = acc;
}

// ---------------------------------------------------------------------------
// Dual-batched f32 GEMM: blockIdx.y selects problem {0,1}. Each: C=A@B(+bias)(relu)
// 128x128 tile, BK=32, 256 threads, 8x8/thread.
// B-fragment SPLIT (cols tc*4 and 64+tc*4): 16 read addrs spread over all 32
// banks = 2-way = free (was 4-way conflicted at tc*8).
// Register prefetch of next tile between barrier and compute hides global lat.
__global__ __launch_bounds__(256) void gemm128_dual(
    const float* __restrict__ A0, const float* __restrict__ B0,
    float* __restrict__ C0, const float* __restrict__ bias0, int relu0,
    const float* __restrict__ A1, const float* __restrict__ B1,
    float* __restrict__ C1, const float* __restrict__ bias1, int relu1,
    int M, int K, int Nw) {
    __shared__ float As[32][132];   // [k][row], stride 132 keeps b128 align
    __shared__ float Bs[32][132];   // [k][col]
    const float* A; const float* B; float* C; const float* bias; int relu;
    if (blockIdx.y == 0) { A = A0; B = B0; C = C0; bias = bias0; relu = relu0; }
    else                 { A = A1; B = B1; C = C1; bias = bias1; relu = relu1; }
    const int m0 = blockIdx.x * 128;
    const int tid = threadIdx.x;
    const int tr = tid >> 4, tc = tid & 15;   // 16x16 threads, 8x8 each
    float acc[8][8] = {};

    float4 rA[4], rB[4];
    // prefetch tile 0
    #pragma unroll
    for (int p = 0; p < 4; p++) {
        int f = tid + 256 * p;
        int row = f >> 3, kq = f & 7;
        int grow = m0 + row;
        rA[p] = (grow < M) ? *reinterpret_cast<const float4*>(&A[(long)grow * K + kq * 4])
                           : make_float4(0.f, 0.f, 0.f, 0.f);
        int kk = f >> 5, nq = f & 31;
        rB[p] = *reinterpret_cast<const float4*>(&B[(long)kk * Nw + nq * 4]);
    }
    for (int k0 = 0; k0 < K; k0 += 32) {
        // write staged regs -> LDS (A transposed)
        #pragma unroll
        for (int p = 0; p < 4; p++) {
            int f = tid + 256 * p;
            int row = f >> 3, kq = f & 7;
            As[kq * 4 + 0][row] = rA[p].x;
            As[kq * 4 + 1][row] = rA[p].y;
            As[kq * 4 + 2][row] = rA[p].z;
            As[kq * 4 + 3][row] = rA[p].w;
            int kk = f >> 5, nq = f & 31;
            *reinterpret_cast<float4*>(&Bs[kk][nq * 4]) = rB[p];
        }
        __syncthreads();
        // prefetch next tile into regs (overlaps with compute below)
        if (k0 + 32 < K) {
            #pragma unroll
            for (int p = 0; p < 4; p++) {
                int f = tid + 256 * p;
                int row = f >> 3, kq = f & 7;
                int grow = m0 + row;
                rA[p] = (grow < M)
                    ? *reinterpret_cast<const float4*>(&A[(long)grow * K + k0 + 32 + kq * 4])
                    : make_float4(0.f, 0.f, 0.f, 0.f);
                int kk = f >> 5, nq = f & 31;
                rB[p] = *reinterpret_cast<const float4*>(&B[(long)(k0 + 32 + kk) * Nw + nq * 4]);
            }
        }
        #pragma unroll
        for (int k = 0; k < 32; k++) {
            const float4 a0 = *reinterpret_cast<const float4*>(&As[k][tr * 8]);
            const float4 a1 = *reinterpret_cast<const float4*>(&As[k][tr * 8 + 4]);
            const float4 b0 = *reinterpret_cast<const float4*>(&Bs[k][tc * 4]);
            const float4 b1 = *reinterpret_cast<const float4*>(&Bs[k][64 + tc * 4]);
            const float a[8] = {a0.x, a0.y, a0.z, a0.w, a1.x, a1.y, a1.z, a1.w};
            const float b[8] = {b0.x, b0.y, b0.z, b0.w, b1.x, b1.y, b1.z, b1.w};
            #pragma unroll
            for (int i = 0; i < 8; i++)
                #pragma unroll
                for (int j = 0; j < 8; j++)
                    acc[i][j] += a[i] * b[j];
        }
        __syncthreads();
    }
    float bv[8];
    #pragma unroll
    for (int j = 0; j < 4; j++) {
        bv[j]     = bias ? bias[tc * 4 + j]      : 0.f;
        bv[j + 4] = bias ? bias[64 + tc * 4 + j] : 0.f;
    }
    #pragma unroll
    for (int i = 0; i < 8; i++) {
        int grow = m0 + tr * 8 + i;
        if (grow >= M) continue;
        float o[8];
        #pragma unroll
        for (int j = 0; j < 8; j++) {
            o[j] = acc[i][j] + bv[j];
            if (relu) o[j] = fmaxf(o[j], 0.f);
        }
        float* cp = &C[(long)grow * Nw];
        *reinterpret_cast<float4*>(cp + tc * 4)      = make_float4(o[0], o[1], o[2], o[3]);
        *reinterpret_cast<float4*>(cp + 64 + tc * 4) = make_float4(o[4], o[5], o[6], o[7]);
    }
}

// ---------------------------------------------------------------------------
// Final fused: h = relu(concat(g2, hl2)); logits = h@Wf+bf; softmax.
// g2 already contains gcn2 sum + self-loop + bg2.
// Block = 256 thr = 64 nodes x 4 colgroups(10 cols).
__global__ __launch_bounds__(256) void final_fused(
    const float* __restrict__ g2, const float* __restrict__ hl2,
    const float* __restrict__ Wf, const float* __restrict__ bf,
    float* __restrict__ out) {
    __shared__ float WfS[2 * HH * DOUT];   // 256x40 = 40KB
    __shared__ float bfS[DOUT];
    __shared__ float hs[64][33];
    const int tid = threadIdx.x;
    for (int p = tid; p < 2 * HH * DOUT; p += 256) WfS[p] = Wf[p];
    if (tid < DOUT) bfS[tid] = bf[tid];
    const int node0 = blockIdx.x * 64;
    const int nl = tid >> 2;   // local node 0..63
    const int cg = tid & 3;    // col group: cols cg*10 .. +9
    float acc[10] = {};
    for (int kt = 0; kt < 8; kt++) {
        __syncthreads();
        #pragma unroll
        for (int p = 0; p < 8; p++) {   // stage h chunk [64][32]
            int id = tid + 256 * p;
            int r = id >> 5, c = id & 31;
            int gn = node0 + r;
            int f = kt * 32 + c;
            float v = 0.f;
            if (gn < NN) {
                if (f < HH) v = fmaxf(g2[(long)gn * HH + f], 0.f);
                else        v = fmaxf(hl2[(long)gn * HH + (f - HH)], 0.f);
            }
            hs[r][c] = v;
        }
        __syncthreads();
        #pragma unroll
        for (int k = 0; k < 32; k++) {
            float hv = hs[nl][k];
            const float* wrow = &WfS[(kt * 32 + k) * DOUT + cg * 10];
            #pragma unroll
            for (int j = 0; j < 10; j++) acc[j] += hv * wrow[j];
        }
    }
    #pragma unroll
    for (int j = 0; j < 10; j++) acc[j] += bfS[cg * 10 + j];
    // softmax over 40 = reduce across the 4 lanes of this node
    float m = acc[0];
    #pragma unroll
    for (int j = 1; j < 10; j++) m = fmaxf(m, acc[j]);
    m = fmaxf(m, __shfl_xor(m, 1));
    m = fmaxf(m, __shfl_xor(m, 2));
    float e[10], ssum = 0.f;
    #pragma unroll
    for (int j = 0; j < 10; j++) { e[j] = expf(acc[j] - m); ssum += e[j]; }
    ssum += __shfl_xor(ssum, 1);
    ssum += __shfl_xor(ssum, 2);
    float inv = 1.f / ssum;
    int gn = node0 + nl;
    if (gn < NN) {
        float* lo = out + (long)gn * DOUT + cg * 10;
        float* po = out + (long)NN * DOUT + (long)gn * DOUT + cg * 10;
        #pragma unroll
        for (int j = 0; j < 10; j++) { lo[j] = acc[j]; po[j] = e[j] * inv; }
    }
}

// ---------------------------------------------------------------------------
extern "C" void kernel_launch(void* const* d_in, const int* in_sizes, int n_in,
                              void* d_out, int out_size, void* d_ws, size_t ws_size,
                              hipStream_t stream) {
    const float* x   = (const float*)d_in[0];
    const int*   ei  = (const int*)d_in[1];
    const float* Wg1 = (const float*)d_in[2];
    const float* bg1 = (const float*)d_in[3];
    const float* Wg2 = (const float*)d_in[4];
    const float* bg2 = (const float*)d_in[5];
    const float* Wl1 = (const float*)d_in[6];
    const float* bl1 = (const float*)d_in[7];
    const float* Wl2 = (const float*)d_in[8];
    const float* bl2 = (const float*)d_in[9];
    const float* Wf  = (const float*)d_in[10];
    const float* bf  = (const float*)d_in[11];
    float* out = (float*)d_out;

    const int* src = ei;            // edge_index[0]
    const int* dst = ei + NE;       // edge_index[1]

    // Workspace layout. Floats first (16B aligned), then ints. ~110 MB.
    float* ws   = (float*)d_ws;
    float* dinv = ws;                         // NN_PAD
    float* hg   = dinv + NN_PAD;              // NN*HH   (x@Wg1; later hg2)
    float* hl   = hg + (long)NN * HH;         // NN*HH   (relu(x@Wl1+bl1))
    float* h1   = hl + (long)NN * HH;         // NN*HH   (gcn1 out; later g2)
    float* hl2  = h1 + (long)NN * HH;         // NN*HH
    float* csr_norm = hl2 + (long)NN * HH;    // NE
    int* cnt     = (int*)(csr_norm + NE);     // NN_PAD
    int* incl    = cnt + NN_PAD;              // NN_PAD
    int* bsum    = incl + NN_PAD;             // 256
    int* rowptr  = bsum + 256;                // NN_PAD (uses NN+1)
    int* cursor  = rowptr + NN_PAD;           // NN_PAD
    int* csr_src = cursor + NN_PAD;           // NE

    const int NB = NN_PAD / 256;              // 196

    // ---- CSR build (per call; ws is re-poisoned before every launch) ----
    hipMemsetAsync(cnt, 0, NN_PAD * sizeof(int), stream);
    hipMemsetAsync(cursor, 0, NN_PAD * sizeof(int), stream);
    k_cnt<<<(NE + 255) / 256, 256, 0, stream>>>(dst, cnt);
    scan_part<<<NB, 256, 0, stream>>>(cnt, incl, bsum, dinv);
    scan_bsum<<<1, 256, 0, stream>>>(bsum, NB);
    scan_final<<<NB, 256, 0, stream>>>(incl, cnt, bsum, rowptr);
    fill_csr<<<(NE + 255) / 256, 256, 0, stream>>>(src, dst, dinv, rowptr,
                                                   cursor, csr_src, csr_norm);

    // ---- Layer 1 GEMMs (batched): hg = x@Wg1 ; hl = relu(x@Wl1+bl1) ----
    dim3 g1((NN + 127) / 128, 2);
    gemm128_dual<<<g1, 256, 0, stream>>>(
        x, Wg1, hg, nullptr, 0,
        x, Wl1, hl, bl1, 1,
        NN, DIN, HH);

    // ---- GCN layer 1 aggregation (fused self-loop + bias + relu) ----
    gather_csr<<<NN / 4, 256, 0, stream>>>(
        rowptr, csr_src, csr_norm, dinv, hg, bg1, h1, 1);

    // ---- Layer 2 GEMMs (batched): hg2 = h1@Wg2 ; hl2 = hl@Wl2+bl2 ----
    gemm128_dual<<<g1, 256, 0, stream>>>(
        h1, Wg2, hg, nullptr, 0,
        hl, Wl2, hl2, bl2, 0,
        NN, HH, HH);

    // ---- GCN layer 2 aggregation (fused self-loop + bg2, no relu) ----
    gather_csr<<<NN / 4, 256, 0, stream>>>(
        rowptr, csr_src, csr_norm, dinv, hg, bg2, h1, 0);

    // ---- Final: concat + relu + [256->40] GEMM + softmax ----
    final_fused<<<(NN + 63) / 64, 256, 0, stream>>>(h1, hl2, Wf, bf, out);
}

// Round 7
// 445.303 us; speedup vs baseline: 1.2548x; 1.2548x over previous
//
#include <hip/hip_runtime.h>
#include <math.h>

// Problem constants (match reference)
#define NN 50000
#define NE 800000
#define DIN 256
#define HH 128      // H1 == H2 == 128
#define DOUT 40
#define NN_PAD 50176   // NN rounded to 256

typedef __attribute__((ext_vector_type(8))) short short8;
typedef __attribute__((ext_vector_type(8))) unsigned short ushort8;
typedef __attribute__((ext_vector_type(4))) float f32x4;

// RNE f32 -> bf16 (as ushort), and back
__device__ __forceinline__ unsigned short f2bf(float f) {
    unsigned int u = __float_as_uint(f);
    unsigned int r = (u + 0x7fffu + ((u >> 16) & 1u)) >> 16;
    return (unsigned short)r;
}
__device__ __forceinline__ float bf2f(unsigned short h) {
    return __uint_as_float(((unsigned int)h) << 16);
}

// ---------------------------------------------------------------------------
// CSR build step 1: in-degree count (self-loop handled as +1 later)
__global__ __launch_bounds__(256) void k_cnt(const int* __restrict__ dst,
                                             int* __restrict__ cnt) {
    int e = blockIdx.x * 256 + threadIdx.x;
    if (e < NE) atomicAdd(&cnt[dst[e]], 1);
}

// CSR build step 2a: per-256-block inclusive scan + block sums; fused dinv
__global__ __launch_bounds__(256) void scan_part(const int* __restrict__ cnt,
                                                 int* __restrict__ incl,
                                                 int* __restrict__ bsum,
                                                 float* __restrict__ dinv) {
    __shared__ int s[256];
    int t = threadIdx.x;
    int id = blockIdx.x * 256 + t;
    int c = cnt[id];                   // cnt padded to NN_PAD, pad = 0
    dinv[id] = rsqrtf((float)c + 1.0f);
    s[t] = c;
    __syncthreads();
    #pragma unroll
    for (int off = 1; off < 256; off <<= 1) {
        int v = (t >= off) ? s[t - off] : 0;
        __syncthreads();
        s[t] += v;
        __syncthreads();
    }
    incl[id] = s[t];
    if (t == 255) bsum[blockIdx.x] = s[255];
}

// CSR build step 2b: exclusive scan of block sums (single block, nb<=256)
__global__ __launch_bounds__(256) void scan_bsum(int* __restrict__ bsum, int nb) {
    __shared__ int s[256];
    int t = threadIdx.x;
    int orig = (t < nb) ? bsum[t] : 0;
    s[t] = orig;
    __syncthreads();
    #pragma unroll
    for (int off = 1; off < 256; off <<= 1) {
        int v = (t >= off) ? s[t - off] : 0;
        __syncthreads();
        s[t] += v;
        __syncthreads();
    }
    if (t < nb) bsum[t] = s[t] - orig;   // exclusive
}

// CSR build step 2c: global exclusive rowptr
__global__ __launch_bounds__(256) void scan_final(const int* __restrict__ incl,
                                                  const int* __restrict__ cnt,
                                                  const int* __restrict__ bsum,
                                                  int* __restrict__ rowptr) {
    int id = blockIdx.x * 256 + threadIdx.x;
    if (id < NN) rowptr[id] = incl[id] - cnt[id] + bsum[id >> 8];
    if (id == 0) rowptr[NN] = NE;
}

// CSR build step 3: fill (src index + precomputed edge norm)
__global__ __launch_bounds__(256) void fill_csr(
    const int* __restrict__ src, const int* __restrict__ dst,
    const float* __restrict__ dinv, const int* __restrict__ rowptr,
    int* __restrict__ cursor, int* __restrict__ csr_src,
    float* __restrict__ csr_norm) {
    int e = blockIdx.x * 256 + threadIdx.x;
    if (e >= NE) return;
    int s = src[e], d = dst[e];
    int pos = rowptr[d] + atomicAdd(&cursor[d], 1);
    csr_src[pos] = s;
    csr_norm[pos] = dinv[s] * dinv[d];
}

// ---------------------------------------------------------------------------
// Weight transpose + bf16 hi/lo split: W[K][128] f32 -> Wt_hi/lo[128][K] bf16.
// blockIdx.y picks one of 4 weights; slot stride 65536 ushorts (hi then lo 32768).
__global__ __launch_bounds__(256) void conv_w(
    const float* __restrict__ W0, const float* __restrict__ W1,
    const float* __restrict__ W2, const float* __restrict__ W3,
    unsigned short* __restrict__ wt) {
    int y = blockIdx.y;
    const float* W = (y == 0) ? W0 : (y == 1) ? W1 : (y == 2) ? W2 : W3;
    int K = (y < 2) ? DIN : HH;
    unsigned short* hi = wt + y * 65536;
    unsigned short* lo = hi + 32768;
    int idx = blockIdx.x * 256 + threadIdx.x;
    if (idx >= K * HH) return;
    int k = idx >> 7, n = idx & 127;
    float f = W[idx];
    unsigned short h = f2bf(f);
    hi[n * K + k] = h;
    lo[n * K + k] = f2bf(f - bf2f(h));
}

// ---------------------------------------------------------------------------
// Gather aggregation: out[d] = sum_{e: dst=d} h[src]*norm + h[d]*dinv[d]^2
//   (+ bias) (+ optional relu).  One node per wave (64 lanes x float2);
//   node index wave-uniform -> csr loads become scalar s_loads.
__global__ __launch_bounds__(256) void gather_csr(
    const int* __restrict__ rowptr, const int* __restrict__ csr_src,
    const float* __restrict__ csr_norm, const float* __restrict__ dinv,
    const float* __restrict__ h, const float* __restrict__ bias,
    float* __restrict__ out, int relu) {
    int node = blockIdx.x * 4 + (threadIdx.x >> 6);   // 12500 blocks x 4 waves
    node = __builtin_amdgcn_readfirstlane(node);      // force SGPR (uniform)
    int lane = threadIdx.x & 63;
    float dd = dinv[node];
    float sl = dd * dd;                               // self-loop norm
    const float2 hv = *reinterpret_cast<const float2*>(&h[(long)node * HH + lane * 2]);
    float2 acc = make_float2(hv.x * sl, hv.y * sl);
    int beg = rowptr[node], end = rowptr[node + 1];
    int i = beg;
    for (; i + 4 <= end; i += 4) {
        int s0 = csr_src[i],     s1 = csr_src[i + 1];
        int s2 = csr_src[i + 2], s3 = csr_src[i + 3];
        float n0 = csr_norm[i],     n1 = csr_norm[i + 1];
        float n2 = csr_norm[i + 2], n3 = csr_norm[i + 3];
        const float2 v0 = *reinterpret_cast<const float2*>(&h[(long)s0 * HH + lane * 2]);
        const float2 v1 = *reinterpret_cast<const float2*>(&h[(long)s1 * HH + lane * 2]);
        const float2 v2 = *reinterpret_cast<const float2*>(&h[(long)s2 * HH + lane * 2]);
        const float2 v3 = *reinterpret_cast<const float2*>(&h[(long)s3 * HH + lane * 2]);
        acc.x += v0.x * n0; acc.y += v0.y * n0;
        acc.x += v1.x * n1; acc.y += v1.y * n1;
        acc.x += v2.x * n2; acc.y += v2.y * n2;
        acc.x += v3.x * n3; acc.y += v3.y * n3;
    }
    for (; i < end; i++) {
        int s0 = csr_src[i];
        float n0 = csr_norm[i];
        const float2 v0 = *reinterpret_cast<const float2*>(&h[(long)s0 * HH + lane * 2]);
        acc.x += v0.x * n0; acc.y += v0.y * n0;
    }
    const float2 bv = *reinterpret_cast<const float2*>(&bias[lane * 2]);
    acc.x += bv.x; acc.y += bv.y;
    if (relu) { acc.x = fmaxf(acc.x, 0.f); acc.y = fmaxf(acc.y, 0.f); }
    *reinterpret_cast<float2*>(&out[(long)node * HH + lane * 2]) = acc;
}

// ---------------------------------------------------------------------------
// Dual-batched MFMA GEMM (bf16x2 split-precision): C[M,128] = A[M,K] @ W[K,128]
// (+bias)(+relu), f32 in/out. A is split hi/lo bf16 ON THE FLY during LDS
// staging; W comes pre-transposed+split ([128][K] bf16 hi/lo).
// acc += Alo*Bhi + Ahi*Blo + Ahi*Bhi  (3x mfma_f32_16x16x32_bf16, f32 acc).
// Tile 128x128, BK=32, 4 waves; wave w owns rows w*32..w*32+31 (2 row-blocks
// of 16) x all 8 col-blocks. Frag mappings per m89-verified guide layout:
//   A: row=l&15, k=(l>>4)*8+j ; B(from [col][k] LDS): col=l&15, k=(l>>4)*8+j
//   C/D: col=l&15, row=(l>>4)*4+j
__global__ __launch_bounds__(256) void gemm_mfma_dual(
    const float* __restrict__ A0, const unsigned short* __restrict__ Whi0,
    const unsigned short* __restrict__ Wlo0, float* __restrict__ C0,
    const float* __restrict__ bias0, int relu0,
    const float* __restrict__ A1, const unsigned short* __restrict__ Whi1,
    const unsigned short* __restrict__ Wlo1, float* __restrict__ C1,
    const float* __restrict__ bias1, int relu1,
    int M, int K) {
    __shared__ unsigned short As_hi[128][40];   // [row][k], stride 40 (80B)
    __shared__ unsigned short As_lo[128][40];
    __shared__ unsigned short Bs_hi[128][40];   // [col][k]
    __shared__ unsigned short Bs_lo[128][40];
    const float* A; const unsigned short* Whi; const unsigned short* Wlo;
    float* C; const float* bias; int relu;
    if (blockIdx.y == 0) { A = A0; Whi = Whi0; Wlo = Wlo0; C = C0; bias = bias0; relu = relu0; }
    else                 { A = A1; Whi = Whi1; Wlo = Wlo1; C = C1; bias = bias1; relu = relu1; }
    const int m0 = blockIdx.x * 128;
    const int tid = threadIdx.x;
    const int w = tid >> 6, l = tid & 63;
    const int lrow = l & 15, lk8 = (l >> 4) * 8;

    f32x4 acc[2][8];
    #pragma unroll
    for (int rb = 0; rb < 2; rb++)
        #pragma unroll
        for (int cb = 0; cb < 8; cb++) acc[rb][cb] = (f32x4){0.f, 0.f, 0.f, 0.f};

    for (int k0 = 0; k0 < K; k0 += 32) {
        // ---- stage A (f32 -> bf16 hi/lo) : 128 rows x 32 k ----
        #pragma unroll
        for (int p = 0; p < 2; p++) {
            int row = (tid >> 2) + p * 64;
            int q = tid & 3;
            int grow = m0 + row;
            float4 a0 = make_float4(0.f, 0.f, 0.f, 0.f);
            float4 a1 = make_float4(0.f, 0.f, 0.f, 0.f);
            if (grow < M) {
                const float* ap = &A[(long)grow * K + k0 + q * 8];
                a0 = *reinterpret_cast<const float4*>(ap);
                a1 = *reinterpret_cast<const float4*>(ap + 4);
            }
            const float v[8] = {a0.x, a0.y, a0.z, a0.w, a1.x, a1.y, a1.z, a1.w};
            ushort8 hi8, lo8;
            #pragma unroll
            for (int j = 0; j < 8; j++) {
                unsigned short h = f2bf(v[j]);
                hi8[j] = h;
                lo8[j] = f2bf(v[j] - bf2f(h));
            }
            *reinterpret_cast<ushort8*>(&As_hi[row][q * 8]) = hi8;
            *reinterpret_cast<ushort8*>(&As_lo[row][q * 8]) = lo8;
        }
        // ---- stage B (pre-split bf16, [col][k]) ----
        #pragma unroll
        for (int p = 0; p < 2; p++) {
            int n = (tid >> 2) + p * 64;
            int q = tid & 3;
            *reinterpret_cast<ushort8*>(&Bs_hi[n][q * 8]) =
                *reinterpret_cast<const ushort8*>(&Whi[(long)n * K + k0 + q * 8]);
            *reinterpret_cast<ushort8*>(&Bs_lo[n][q * 8]) =
                *reinterpret_cast<const ushort8*>(&Wlo[(long)n * K + k0 + q * 8]);
        }
        __syncthreads();
        // ---- MFMA: 2 row-blocks x 8 col-blocks x 3 products ----
        short8 ahi[2], alo[2];
        #pragma unroll
        for (int rb = 0; rb < 2; rb++) {
            int ar = w * 32 + rb * 16 + lrow;
            ahi[rb] = *reinterpret_cast<const short8*>(&As_hi[ar][lk8]);
            alo[rb] = *reinterpret_cast<const short8*>(&As_lo[ar][lk8]);
        }
        #pragma unroll
        for (int cb = 0; cb < 8; cb++) {
            int br = cb * 16 + lrow;
            short8 bhi = *reinterpret_cast<const short8*>(&Bs_hi[br][lk8]);
            short8 blo = *reinterpret_cast<const short8*>(&Bs_lo[br][lk8]);
            #pragma unroll
            for (int rb = 0; rb < 2; rb++) {
                f32x4 t = __builtin_amdgcn_mfma_f32_16x16x32_bf16(alo[rb], bhi, acc[rb][cb], 0, 0, 0);
                t = __builtin_amdgcn_mfma_f32_16x16x32_bf16(ahi[rb], blo, t, 0, 0, 0);
                acc[rb][cb] = __builtin_amdgcn_mfma_f32_16x16x32_bf16(ahi[rb], bhi, t, 0, 0, 0);
            }
        }
        __syncthreads();
    }
    // ---- epilogue: bias + relu + f32 store ----
    float bv[8];
    #pragma unroll
    for (int cb = 0; cb < 8; cb++) bv[cb] = bias ? bias[cb * 16 + lrow] : 0.f;
    #pragma unroll
    for (int rb = 0; rb < 2; rb++) {
        #pragma unroll
        for (int j = 0; j < 4; j++) {
            int grow = m0 + w * 32 + rb * 16 + (l >> 4) * 4 + j;
            if (grow < M) {
                #pragma unroll
                for (int cb = 0; cb < 8; cb++) {
                    float o = acc[rb][cb][j] + bv[cb];
                    if (relu) o = fmaxf(o, 0.f);
                    C[(long)grow * HH + cb * 16 + lrow] = o;
                }
            }
        }
    }
}

// ---------------------------------------------------------------------------
// Final fused: h = relu(concat(g2, hl2)); logits = h@Wf+bf; softmax.
// g2 already contains gcn2 sum + self-loop + bg2.
// Block = 256 thr = 64 nodes x 4 colgroups(10 cols).
__global__ __launch_bounds__(256) void final_fused(
    const float* __restrict__ g2, const float* __restrict__ hl2,
    const float* __restrict__ Wf, const float* __restrict__ bf,
    float* __restrict__ out) {
    __shared__ float WfS[2 * HH * DOUT];   // 256x40 = 40KB
    __shared__ float bfS[DOUT];
    __shared__ float hs[64][33];
    const int tid = threadIdx.x;
    for (int p = tid; p < 2 * HH * DOUT; p += 256) WfS[p] = Wf[p];
    if (tid < DOUT) bfS[tid] = bf[tid];
    const int node0 = blockIdx.x * 64;
    const int nl = tid >> 2;   // local node 0..63
    const int cg = tid & 3;    // col group: cols cg*10 .. +9
    float acc[10] = {};
    for (int kt = 0; kt < 8; kt++) {
        __syncthreads();
        #pragma unroll
        for (int p = 0; p < 8; p++) {   // stage h chunk [64][32]
            int id = tid + 256 * p;
            int r = id >> 5, c = id & 31;
            int gn = node0 + r;
            int f = kt * 32 + c;
            float v = 0.f;
            if (gn < NN) {
                if (f < HH) v = fmaxf(g2[(long)gn * HH + f], 0.f);
                else        v = fmaxf(hl2[(long)gn * HH + (f - HH)], 0.f);
            }
            hs[r][c] = v;
        }
        __syncthreads();
        #pragma unroll
        for (int k = 0; k < 32; k++) {
            float hv = hs[nl][k];
            const float* wrow = &WfS[(kt * 32 + k) * DOUT + cg * 10];
            #pragma unroll
            for (int j = 0; j < 10; j++) acc[j] += hv * wrow[j];
        }
    }
    #pragma unroll
    for (int j = 0; j < 10; j++) acc[j] += bfS[cg * 10 + j];
    // softmax over 40 = reduce across the 4 lanes of this node
    float m = acc[0];
    #pragma unroll
    for (int j = 1; j < 10; j++) m = fmaxf(m, acc[j]);
    m = fmaxf(m, __shfl_xor(m, 1));
    m = fmaxf(m, __shfl_xor(m, 2));
    float e[10], ssum = 0.f;
    #pragma unroll
    for (int j = 0; j < 10; j++) { e[j] = expf(acc[j] - m); ssum += e[j]; }
    ssum += __shfl_xor(ssum, 1);
    ssum += __shfl_xor(ssum, 2);
    float inv = 1.f / ssum;
    int gn = node0 + nl;
    if (gn < NN) {
        float* lo = out + (long)gn * DOUT + cg * 10;
        float* po = out + (long)NN * DOUT + (long)gn * DOUT + cg * 10;
        #pragma unroll
        for (int j = 0; j < 10; j++) { lo[j] = acc[j]; po[j] = e[j] * inv; }
    }
}

// ---------------------------------------------------------------------------
extern "C" void kernel_launch(void* const* d_in, const int* in_sizes, int n_in,
                              void* d_out, int out_size, void* d_ws, size_t ws_size,
                              hipStream_t stream) {
    const float* x   = (const float*)d_in[0];
    const int*   ei  = (const int*)d_in[1];
    const float* Wg1 = (const float*)d_in[2];
    const float* bg1 = (const float*)d_in[3];
    const float* Wg2 = (const float*)d_in[4];
    const float* bg2 = (const float*)d_in[5];
    const float* Wl1 = (const float*)d_in[6];
    const float* bl1 = (const float*)d_in[7];
    const float* Wl2 = (const float*)d_in[8];
    const float* bl2 = (const float*)d_in[9];
    const float* Wf  = (const float*)d_in[10];
    const float* bf  = (const float*)d_in[11];
    float* out = (float*)d_out;

    const int* src = ei;            // edge_index[0]
    const int* dst = ei + NE;       // edge_index[1]

    // Workspace layout. Floats first (16B aligned), then ints, then bf16 wt.
    float* ws   = (float*)d_ws;
    float* dinv = ws;                         // NN_PAD
    float* hg   = dinv + NN_PAD;              // NN*HH   (x@Wg1; later hg2)
    float* hl   = hg + (long)NN * HH;         // NN*HH   (relu(x@Wl1+bl1))
    float* h1   = hl + (long)NN * HH;         // NN*HH   (gcn1 out; later g2)
    float* hl2  = h1 + (long)NN * HH;         // NN*HH
    float* csr_norm = hl2 + (long)NN * HH;    // NE
    int* cnt     = (int*)(csr_norm + NE);     // NN_PAD
    int* incl    = cnt + NN_PAD;              // NN_PAD
    int* bsum    = incl + NN_PAD;             // 256
    int* rowptr  = bsum + 256;                // NN_PAD (uses NN+1)
    int* cursor  = rowptr + NN_PAD;           // NN_PAD
    int* csr_src = cursor + NN_PAD;           // NE
    unsigned short* wt = (unsigned short*)(csr_src + NE);  // 4*65536 ushort
    unsigned short* wg1_hi = wt;              unsigned short* wg1_lo = wt + 32768;
    unsigned short* wl1_hi = wt + 65536;      unsigned short* wl1_lo = wt + 98304;
    unsigned short* wg2_hi = wt + 131072;     unsigned short* wg2_lo = wt + 163840;
    unsigned short* wl2_hi = wt + 196608;     unsigned short* wl2_lo = wt + 229376;

    const int NB = NN_PAD / 256;              // 196

    // ---- CSR build + weight split (per call) ----
    hipMemsetAsync(cnt, 0, NN_PAD * sizeof(int), stream);
    hipMemsetAsync(cursor, 0, NN_PAD * sizeof(int), stream);
    k_cnt<<<(NE + 255) / 256, 256, 0, stream>>>(dst, cnt);
    scan_part<<<NB, 256, 0, stream>>>(cnt, incl, bsum, dinv);
    scan_bsum<<<1, 256, 0, stream>>>(bsum, NB);
    scan_final<<<NB, 256, 0, stream>>>(incl, cnt, bsum, rowptr);
    fill_csr<<<(NE + 255) / 256, 256, 0, stream>>>(src, dst, dinv, rowptr,
                                                   cursor, csr_src, csr_norm);
    conv_w<<<dim3(128, 4), 256, 0, stream>>>(Wg1, Wl1, Wg2, Wl2, wt);

    // ---- Layer 1 GEMMs (MFMA): hg = x@Wg1 ; hl = relu(x@Wl1+bl1) ----
    dim3 g1((NN + 127) / 128, 2);
    gemm_mfma_dual<<<g1, 256, 0, stream>>>(
        x, wg1_hi, wg1_lo, hg, nullptr, 0,
        x, wl1_hi, wl1_lo, hl, bl1, 1,
        NN, DIN);

    // ---- GCN layer 1 aggregation (fused self-loop + bias + relu) ----
    gather_csr<<<NN / 4, 256, 0, stream>>>(
        rowptr, csr_src, csr_norm, dinv, hg, bg1, h1, 1);

    // ---- Layer 2 GEMMs (MFMA): hg2 = h1@Wg2 ; hl2 = hl@Wl2+bl2 ----
    gemm_mfma_dual<<<g1, 256, 0, stream>>>(
        h1, wg2_hi, wg2_lo, hg, nullptr, 0,
        hl, wl2_hi, wl2_lo, hl2, bl2, 0,
        NN, HH);

    // ---- GCN layer 2 aggregation (fused self-loop + bg2, no relu) ----
    gather_csr<<<NN / 4, 256, 0, stream>>>(
        rowptr, csr_src, csr_norm, dinv, hg, bg2, h1, 0);

    // ---- Final: concat + relu + [256->40] GEMM + softmax ----
    final_fused<<<(NN + 63) / 64, 256, 0, stream>>>(h1, hl2, Wf, bf, out);
}

// Round 10
// 397.861 us; speedup vs baseline: 1.4044x; 1.1192x over previous
//
#include <hip/hip_runtime.h>
#include <math.h>

// Problem constants (match reference)
#define NN 50000
#define NE 800000
#define DIN 256
#define HH 128      // H1 == H2 == 128
#define DOUT 40
#define NN_PAD 50176   // NN rounded to 256

typedef __attribute__((ext_vector_type(8))) short short8;
typedef __attribute__((ext_vector_type(8))) unsigned short ushort8;
typedef __attribute__((ext_vector_type(4))) float f32x4;

// RNE f32 -> bf16 (as ushort), and back
__device__ __forceinline__ unsigned short f2bf(float f) {
    unsigned int u = __float_as_uint(f);
    unsigned int r = (u + 0x7fffu + ((u >> 16) & 1u)) >> 16;
    return (unsigned short)r;
}
__device__ __forceinline__ float bf2f(unsigned short h) {
    return __uint_as_float(((unsigned int)h) << 16);
}

// ---------------------------------------------------------------------------
// CSR build step 1: in-degree count (self-loop handled as +1 later)
__global__ __launch_bounds__(256) void k_cnt(const int* __restrict__ dst,
                                             int* __restrict__ cnt) {
    int e = blockIdx.x * 256 + threadIdx.x;
    if (e < NE) atomicAdd(&cnt[dst[e]], 1);
}

// CSR build step 2a: per-256-block inclusive scan + block sums; fused dinv
__global__ __launch_bounds__(256) void scan_part(const int* __restrict__ cnt,
                                                 int* __restrict__ incl,
                                                 int* __restrict__ bsum,
                                                 float* __restrict__ dinv) {
    __shared__ int s[256];
    int t = threadIdx.x;
    int id = blockIdx.x * 256 + t;
    int c = cnt[id];                   // cnt padded to NN_PAD, pad = 0
    dinv[id] = rsqrtf((float)c + 1.0f);
    s[t] = c;
    __syncthreads();
    #pragma unroll
    for (int off = 1; off < 256; off <<= 1) {
        int v = (t >= off) ? s[t - off] : 0;
        __syncthreads();
        s[t] += v;
        __syncthreads();
    }
    incl[id] = s[t];
    if (t == 255) bsum[blockIdx.x] = s[255];
}

// CSR build step 2b: exclusive scan of block sums (single block, nb<=256)
__global__ __launch_bounds__(256) void scan_bsum(int* __restrict__ bsum, int nb) {
    __shared__ int s[256];
    int t = threadIdx.x;
    int orig = (t < nb) ? bsum[t] : 0;
    s[t] = orig;
    __syncthreads();
    #pragma unroll
    for (int off = 1; off < 256; off <<= 1) {
        int v = (t >= off) ? s[t - off] : 0;
        __syncthreads();
        s[t] += v;
        __syncthreads();
    }
    if (t < nb) bsum[t] = s[t] - orig;   // exclusive
}

// CSR build step 2c: global exclusive rowptr
__global__ __launch_bounds__(256) void scan_final(const int* __restrict__ incl,
                                                  const int* __restrict__ cnt,
                                                  const int* __restrict__ bsum,
                                                  int* __restrict__ rowptr) {
    int id = blockIdx.x * 256 + threadIdx.x;
    if (id < NN) rowptr[id] = incl[id] - cnt[id] + bsum[id >> 8];
    if (id == 0) rowptr[NN] = NE;
}

// CSR build step 3: fill (src index + precomputed edge norm)
__global__ __launch_bounds__(256) void fill_csr(
    const int* __restrict__ src, const int* __restrict__ dst,
    const float* __restrict__ dinv, const int* __restrict__ rowptr,
    int* __restrict__ cursor, int* __restrict__ csr_src,
    float* __restrict__ csr_norm) {
    int e = blockIdx.x * 256 + threadIdx.x;
    if (e >= NE) return;
    int s = src[e], d = dst[e];
    int pos = rowptr[d] + atomicAdd(&cursor[d], 1);
    csr_src[pos] = s;
    csr_norm[pos] = dinv[s] * dinv[d];
}

// ---------------------------------------------------------------------------
// Weight transpose + bf16 hi/lo split: W[K][128] f32 -> Wt_hi/lo[128][K] bf16.
// blockIdx.y picks one of 4 weights; slot stride 65536 ushorts (hi then lo 32768).
__global__ __launch_bounds__(256) void conv_w(
    const float* __restrict__ W0, const float* __restrict__ W1,
    const float* __restrict__ W2, const float* __restrict__ W3,
    unsigned short* __restrict__ wt) {
    int y = blockIdx.y;
    const float* W = (y == 0) ? W0 : (y == 1) ? W1 : (y == 2) ? W2 : W3;
    int K = (y < 2) ? DIN : HH;
    unsigned short* hi = wt + y * 65536;
    unsigned short* lo = hi + 32768;
    int idx = blockIdx.x * 256 + threadIdx.x;
    if (idx >= K * HH) return;
    int k = idx >> 7, n = idx & 127;
    float f = W[idx];
    unsigned short h = f2bf(f);
    hi[n * K + k] = h;
    lo[n * K + k] = f2bf(f - bf2f(h));
}

// Wf [256][40] f32 -> WfT hi/lo [48][256] bf16 (cols 40..47 zero-padded)
__global__ __launch_bounds__(256) void conv_wf(
    const float* __restrict__ Wf, unsigned short* __restrict__ hi,
    unsigned short* __restrict__ lo) {
    int idx = blockIdx.x * 256 + threadIdx.x;   // 48*256 = 12288
    if (idx >= 48 * 256) return;
    int n = idx >> 8, k = idx & 255;
    float f = (n < DOUT) ? Wf[k * DOUT + n] : 0.f;
    unsigned short h = f2bf(f);
    hi[idx] = h;
    lo[idx] = f2bf(f - bf2f(h));
}

// ---------------------------------------------------------------------------
// Gather aggregation: out[d] = sum_{e: dst=d} h[src]*norm + h[d]*dinv[d]^2
//   (+ bias) (+ optional relu).  One node per wave (64 lanes x float2);
//   node index wave-uniform -> csr loads become scalar s_loads.
__global__ __launch_bounds__(256) void gather_csr(
    const int* __restrict__ rowptr, const int* __restrict__ csr_src,
    const float* __restrict__ csr_norm, const float* __restrict__ dinv,
    const float* __restrict__ h, const float* __restrict__ bias,
    float* __restrict__ out, int relu) {
    int node = blockIdx.x * 4 + (threadIdx.x >> 6);   // 12500 blocks x 4 waves
    node = __builtin_amdgcn_readfirstlane(node);      // force SGPR (uniform)
    int lane = threadIdx.x & 63;
    float dd = dinv[node];
    float sl = dd * dd;                               // self-loop norm
    const float2 hv = *reinterpret_cast<const float2*>(&h[(long)node * HH + lane * 2]);
    float2 acc = make_float2(hv.x * sl, hv.y * sl);
    int beg = rowptr[node], end = rowptr[node + 1];
    int i = beg;
    for (; i + 4 <= end; i += 4) {
        int s0 = csr_src[i],     s1 = csr_src[i + 1];
        int s2 = csr_src[i + 2], s3 = csr_src[i + 3];
        float n0 = csr_norm[i],     n1 = csr_norm[i + 1];
        float n2 = csr_norm[i + 2], n3 = csr_norm[i + 3];
        const float2 v0 = *reinterpret_cast<const float2*>(&h[(long)s0 * HH + lane * 2]);
        const float2 v1 = *reinterpret_cast<const float2*>(&h[(long)s1 * HH + lane * 2]);
        const float2 v2 = *reinterpret_cast<const float2*>(&h[(long)s2 * HH + lane * 2]);
        const float2 v3 = *reinterpret_cast<const float2*>(&h[(long)s3 * HH + lane * 2]);
        acc.x += v0.x * n0; acc.y += v0.y * n0;
        acc.x += v1.x * n1; acc.y += v1.y * n1;
        acc.x += v2.x * n2; acc.y += v2.y * n2;
        acc.x += v3.x * n3; acc.y += v3.y * n3;
    }
    for (; i < end; i++) {
        int s0 = csr_src[i];
        float n0 = csr_norm[i];
        const float2 v0 = *reinterpret_cast<const float2*>(&h[(long)s0 * HH + lane * 2]);
        acc.x += v0.x * n0; acc.y += v0.y * n0;
    }
    const float2 bv = *reinterpret_cast<const float2*>(&bias[lane * 2]);
    acc.x += bv.x; acc.y += bv.y;
    if (relu) { acc.x = fmaxf(acc.x, 0.f); acc.y = fmaxf(acc.y, 0.f); }
    *reinterpret_cast<float2*>(&out[(long)node * HH + lane * 2]) = acc;
}

// ---------------------------------------------------------------------------
// Dual-batched MFMA GEMM (bf16x2 split-precision): C[M,128] = A[M,K] @ W[K,128]
// (+bias)(+relu), f32 in/out. A is split hi/lo bf16 ON THE FLY during LDS
// staging; W comes pre-transposed+split ([128][K] bf16 hi/lo).
// acc += Alo*Bhi + Ahi*Blo + Ahi*Bhi  (3x mfma_f32_16x16x32_bf16, f32 acc).
__global__ __launch_bounds__(256) void gemm_mfma_dual(
    const float* __restrict__ A0, const unsigned short* __restrict__ Whi0,
    const unsigned short* __restrict__ Wlo0, float* __restrict__ C0,
    const float* __restrict__ bias0, int relu0,
    const float* __restrict__ A1, const unsigned short* __restrict__ Whi1,
    const unsigned short* __restrict__ Wlo1, float* __restrict__ C1,
    const float* __restrict__ bias1, int relu1,
    int M, int K) {
    __shared__ unsigned short As_hi[128][40];   // [row][k], stride 40 (80B)
    __shared__ unsigned short As_lo[128][40];
    __shared__ unsigned short Bs_hi[128][40];   // [col][k]
    __shared__ unsigned short Bs_lo[128][40];
    const float* A; const unsigned short* Whi; const unsigned short* Wlo;
    float* C; const float* bias; int relu;
    if (blockIdx.y == 0) { A = A0; Whi = Whi0; Wlo = Wlo0; C = C0; bias = bias0; relu = relu0; }
    else                 { A = A1; Whi = Whi1; Wlo = Wlo1; C = C1; bias = bias1; relu = relu1; }
    const int m0 = blockIdx.x * 128;
    const int tid = threadIdx.x;
    const int w = tid >> 6, l = tid & 63;
    const int lrow = l & 15, lk8 = (l >> 4) * 8;

    f32x4 acc[2][8];
    #pragma unroll
    for (int rb = 0; rb < 2; rb++)
        #pragma unroll
        for (int cb = 0; cb < 8; cb++) acc[rb][cb] = (f32x4){0.f, 0.f, 0.f, 0.f};

    for (int k0 = 0; k0 < K; k0 += 32) {
        // ---- stage A (f32 -> bf16 hi/lo) : 128 rows x 32 k ----
        #pragma unroll
        for (int p = 0; p < 2; p++) {
            int row = (tid >> 2) + p * 64;
            int q = tid & 3;
            int grow = m0 + row;
            float4 a0 = make_float4(0.f, 0.f, 0.f, 0.f);
            float4 a1 = make_float4(0.f, 0.f, 0.f, 0.f);
            if (grow < M) {
                const float* ap = &A[(long)grow * K + k0 + q * 8];
                a0 = *reinterpret_cast<const float4*>(ap);
                a1 = *reinterpret_cast<const float4*>(ap + 4);
            }
            const float v[8] = {a0.x, a0.y, a0.z, a0.w, a1.x, a1.y, a1.z, a1.w};
            ushort8 hi8, lo8;
            #pragma unroll
            for (int j = 0; j < 8; j++) {
                unsigned short h = f2bf(v[j]);
                hi8[j] = h;
                lo8[j] = f2bf(v[j] - bf2f(h));
            }
            *reinterpret_cast<ushort8*>(&As_hi[row][q * 8]) = hi8;
            *reinterpret_cast<ushort8*>(&As_lo[row][q * 8]) = lo8;
        }
        // ---- stage B (pre-split bf16, [col][k]) ----
        #pragma unroll
        for (int p = 0; p < 2; p++) {
            int n = (tid >> 2) + p * 64;
            int q = tid & 3;
            *reinterpret_cast<ushort8*>(&Bs_hi[n][q * 8]) =
                *reinterpret_cast<const ushort8*>(&Whi[(long)n * K + k0 + q * 8]);
            *reinterpret_cast<ushort8*>(&Bs_lo[n][q * 8]) =
                *reinterpret_cast<const ushort8*>(&Wlo[(long)n * K + k0 + q * 8]);
        }
        __syncthreads();
        // ---- MFMA: 2 row-blocks x 8 col-blocks x 3 products ----
        short8 ahi[2], alo[2];
        #pragma unroll
        for (int rb = 0; rb < 2; rb++) {
            int ar = w * 32 + rb * 16 + lrow;
            ahi[rb] = *reinterpret_cast<const short8*>(&As_hi[ar][lk8]);
            alo[rb] = *reinterpret_cast<const short8*>(&As_lo[ar][lk8]);
        }
        #pragma unroll
        for (int cb = 0; cb < 8; cb++) {
            int br = cb * 16 + lrow;
            short8 bhi = *reinterpret_cast<const short8*>(&Bs_hi[br][lk8]);
            short8 blo = *reinterpret_cast<const short8*>(&Bs_lo[br][lk8]);
            #pragma unroll
            for (int rb = 0; rb < 2; rb++) {
                f32x4 t = __builtin_amdgcn_mfma_f32_16x16x32_bf16(alo[rb], bhi, acc[rb][cb], 0, 0, 0);
                t = __builtin_amdgcn_mfma_f32_16x16x32_bf16(ahi[rb], blo, t, 0, 0, 0);
                acc[rb][cb] = __builtin_amdgcn_mfma_f32_16x16x32_bf16(ahi[rb], bhi, t, 0, 0, 0);
            }
        }
        __syncthreads();
    }
    // ---- epilogue: bias + relu + f32 store ----
    float bv[8];
    #pragma unroll
    for (int cb = 0; cb < 8; cb++) bv[cb] = bias ? bias[cb * 16 + lrow] : 0.f;
    #pragma unroll
    for (int rb = 0; rb < 2; rb++) {
        #pragma unroll
        for (int j = 0; j < 4; j++) {
            int grow = m0 + w * 32 + rb * 16 + (l >> 4) * 4 + j;
            if (grow < M) {
                #pragma unroll
                for (int cb = 0; cb < 8; cb++) {
                    float o = acc[rb][cb][j] + bv[cb];
                    if (relu) o = fmaxf(o, 0.f);
                    C[(long)grow * HH + cb * 16 + lrow] = o;
                }
            }
        }
    }
}

// ---------------------------------------------------------------------------
// Final layer, MFMA, LDS-free: logits = relu(concat(g2,hl2)) @ Wf + bf;
// out = [logits ; softmax(logits)].  A-fragments loaded DIRECTLY from global
// (4 lanes cover each 128B row chunk -> coalesced), concat+relu+bf16-split in
// regs. WfT pre-split [48][256] (cols 40..47 zero). Softmax per row inside the
// 16-lane group that holds its 48 cols (col = cb*16 + (l&15)).
__global__ __launch_bounds__(256) void final_mfma(
    const float* __restrict__ g2, const float* __restrict__ hl2,
    const unsigned short* __restrict__ wfhi, const unsigned short* __restrict__ wflo,
    const float* __restrict__ bf, float* __restrict__ out) {
    const int m0 = blockIdx.x * 128;
    const int tid = threadIdx.x;
    const int w = tid >> 6, l = tid & 63;
    const int lrow = l & 15, lk8 = (l >> 4) * 8;

    f32x4 acc[2][3];
    #pragma unroll
    for (int rb = 0; rb < 2; rb++)
        #pragma unroll
        for (int cb = 0; cb < 3; cb++) acc[rb][cb] = (f32x4){0.f, 0.f, 0.f, 0.f};

    for (int k0 = 0; k0 < 2 * HH; k0 += 32) {
        const float* src = (k0 < HH) ? g2 : hl2;
        const int off = k0 & (HH - 1);
        // B fragments (L2-hot, shared by all blocks)
        short8 bhi[3], blo[3];
        #pragma unroll
        for (int cb = 0; cb < 3; cb++) {
            int br = cb * 16 + lrow;
            bhi[cb] = *reinterpret_cast<const short8*>(&wfhi[br * 256 + k0 + lk8]);
            blo[cb] = *reinterpret_cast<const short8*>(&wflo[br * 256 + k0 + lk8]);
        }
        #pragma unroll
        for (int rb = 0; rb < 2; rb++) {
            int row = m0 + w * 32 + rb * 16 + lrow;
            float4 a0 = make_float4(0.f, 0.f, 0.f, 0.f);
            float4 a1 = make_float4(0.f, 0.f, 0.f, 0.f);
            if (row < NN) {
                const float* ap = &src[(long)row * HH + off + lk8];
                a0 = *reinterpret_cast<const float4*>(ap);
                a1 = *reinterpret_cast<const float4*>(ap + 4);
            }
            const float v[8] = {a0.x, a0.y, a0.z, a0.w, a1.x, a1.y, a1.z, a1.w};
            short8 ahi, alo;
            #pragma unroll
            for (int j = 0; j < 8; j++) {
                float r = fmaxf(v[j], 0.f);           // relu(concat)
                unsigned short h = f2bf(r);
                ahi[j] = (short)h;
                alo[j] = (short)f2bf(r - bf2f(h));
            }
            #pragma unroll
            for (int cb = 0; cb < 3; cb++) {
                f32x4 t = __builtin_amdgcn_mfma_f32_16x16x32_bf16(alo, bhi[cb], acc[rb][cb], 0, 0, 0);
                t = __builtin_amdgcn_mfma_f32_16x16x32_bf16(ahi, blo[cb], t, 0, 0, 0);
                acc[rb][cb] = __builtin_amdgcn_mfma_f32_16x16x32_bf16(ahi, bhi[cb], t, 0, 0, 0);
            }
        }
    }
    // ---- epilogue: bias + softmax within 16-lane group ----
    float bfv[3];
    #pragma unroll
    for (int cb = 0; cb < 3; cb++) {
        int col = cb * 16 + lrow;
        bfv[cb] = (col < DOUT) ? bf[col] : 0.f;
    }
    const bool v2 = (lrow < 8);                       // cb==2 valid only if col<40
    #pragma unroll
    for (int rb = 0; rb < 2; rb++) {
        float lg[3][4];
        #pragma unroll
        for (int cb = 0; cb < 3; cb++)
            #pragma unroll
            for (int j = 0; j < 4; j++) lg[cb][j] = acc[rb][cb][j] + bfv[cb];
        float mx[4], sm[4];
        #pragma unroll
        for (int j = 0; j < 4; j++) {
            mx[j] = fmaxf(lg[0][j], lg[1][j]);
            if (v2) mx[j] = fmaxf(mx[j], lg[2][j]);
        }
        #pragma unroll
        for (int msk = 1; msk <= 8; msk <<= 1)
            #pragma unroll
            for (int j = 0; j < 4; j++) mx[j] = fmaxf(mx[j], __shfl_xor(mx[j], msk));
        float ex[3][4];
        #pragma unroll
        for (int j = 0; j < 4; j++) {
            ex[0][j] = expf(lg[0][j] - mx[j]);
            ex[1][j] = expf(lg[1][j] - mx[j]);
            ex[2][j] = v2 ? expf(lg[2][j] - mx[j]) : 0.f;
            sm[j] = ex[0][j] + ex[1][j] + ex[2][j];
        }
        #pragma unroll
        for (int msk = 1; msk <= 8; msk <<= 1)
            #pragma unroll
            for (int j = 0; j < 4; j++) sm[j] += __shfl_xor(sm[j], msk);
        const int rowb = m0 + w * 32 + rb * 16 + (l >> 4) * 4;
        #pragma unroll
        for (int j = 0; j < 4; j++) {
            int row = rowb + j;
            if (row >= NN) continue;
            float inv = 1.f / sm[j];
            #pragma unroll
            for (int cb = 0; cb < 3; cb++) {
                if (cb == 2 && !v2) continue;
                int col = cb * 16 + lrow;
                out[(long)row * DOUT + col] = lg[cb][j];
                out[(long)NN * DOUT + (long)row * DOUT + col] = ex[cb][j] * inv;
            }
        }
    }
}

// ---------------------------------------------------------------------------
extern "C" void kernel_launch(void* const* d_in, const int* in_sizes, int n_in,
                              void* d_out, int out_size, void* d_ws, size_t ws_size,
                              hipStream_t stream) {
    const float* x   = (const float*)d_in[0];
    const int*   ei  = (const int*)d_in[1];
    const float* Wg1 = (const float*)d_in[2];
    const float* bg1 = (const float*)d_in[3];
    const float* Wg2 = (const float*)d_in[4];
    const float* bg2 = (const float*)d_in[5];
    const float* Wl1 = (const float*)d_in[6];
    const float* bl1 = (const float*)d_in[7];
    const float* Wl2 = (const float*)d_in[8];
    const float* bl2 = (const float*)d_in[9];
    const float* Wf  = (const float*)d_in[10];
    const float* bf  = (const float*)d_in[11];
    float* out = (float*)d_out;

    const int* src = ei;            // edge_index[0]
    const int* dst = ei + NE;       // edge_index[1]

    // Workspace layout. Floats first (16B aligned), then ints, then bf16 wt.
    float* ws   = (float*)d_ws;
    float* dinv = ws;                         // NN_PAD
    float* hg   = dinv + NN_PAD;              // NN*HH   (x@Wg1; later hg2)
    float* hl   = hg + (long)NN * HH;         // NN*HH   (relu(x@Wl1+bl1))
    float* h1   = hl + (long)NN * HH;         // NN*HH   (gcn1 out; later g2)
    float* hl2  = h1 + (long)NN * HH;         // NN*HH
    float* csr_norm = hl2 + (long)NN * HH;    // NE
    int* cnt     = (int*)(csr_norm + NE);     // NN_PAD
    int* incl    = cnt + NN_PAD;              // NN_PAD
    int* bsum    = incl + NN_PAD;             // 256
    int* rowptr  = bsum + 256;                // NN_PAD (uses NN+1)
    int* cursor  = rowptr + NN_PAD;           // NN_PAD
    int* csr_src = cursor + NN_PAD;           // NE
    unsigned short* wt = (unsigned short*)(csr_src + NE);  // 4*65536 ushort
    unsigned short* wg1_hi = wt;              unsigned short* wg1_lo = wt + 32768;
    unsigned short* wl1_hi = wt + 65536;      unsigned short* wl1_lo = wt + 98304;
    unsigned short* wg2_hi = wt + 131072;     unsigned short* wg2_lo = wt + 163840;
    unsigned short* wl2_hi = wt + 196608;     unsigned short* wl2_lo = wt + 229376;
    unsigned short* wf_hi  = wt + 262144;     // 48*256
    unsigned short* wf_lo  = wf_hi + 12288;

    const int NB = NN_PAD / 256;              // 196

    // ---- CSR build + weight split (per call) ----
    hipMemsetAsync(cnt, 0, NN_PAD * sizeof(int), stream);
    hipMemsetAsync(cursor, 0, NN_PAD * sizeof(int), stream);
    k_cnt<<<(NE + 255) / 256, 256, 0, stream>>>(dst, cnt);
    scan_part<<<NB, 256, 0, stream>>>(cnt, incl, bsum, dinv);
    scan_bsum<<<1, 256, 0, stream>>>(bsum, NB);
    scan_final<<<NB, 256, 0, stream>>>(incl, cnt, bsum, rowptr);
    fill_csr<<<(NE + 255) / 256, 256, 0, stream>>>(src, dst, dinv, rowptr,
                                                   cursor, csr_src, csr_norm);
    conv_w<<<dim3(128, 4), 256, 0, stream>>>(Wg1, Wl1, Wg2, Wl2, wt);
    conv_wf<<<48, 256, 0, stream>>>(Wf, wf_hi, wf_lo);

    // ---- Layer 1 GEMMs (MFMA): hg = x@Wg1 ; hl = relu(x@Wl1+bl1) ----
    dim3 g1((NN + 127) / 128, 2);
    gemm_mfma_dual<<<g1, 256, 0, stream>>>(
        x, wg1_hi, wg1_lo, hg, nullptr, 0,
        x, wl1_hi, wl1_lo, hl, bl1, 1,
        NN, DIN);

    // ---- GCN layer 1 aggregation (fused self-loop + bias + relu) ----
    gather_csr<<<NN / 4, 256, 0, stream>>>(
        rowptr, csr_src, csr_norm, dinv, hg, bg1, h1, 1);

    // ---- Layer 2 GEMMs (MFMA): hg2 = h1@Wg2 ; hl2 = hl@Wl2+bl2 ----
    gemm_mfma_dual<<<g1, 256, 0, stream>>>(
        h1, wg2_hi, wg2_lo, hg, nullptr, 0,
        hl, wl2_hi, wl2_lo, hl2, bl2, 0,
        NN, HH);

    // ---- GCN layer 2 aggregation (fused self-loop + bg2, no relu) ----
    gather_csr<<<NN / 4, 256, 0, stream>>>(
        rowptr, csr_src, csr_norm, dinv, hg, bg2, h1, 0);

    // ---- Final: concat + relu + [256->40] MFMA GEMM + softmax (no LDS) ----
    final_mfma<<<(NN + 127) / 128, 256, 0, stream>>>(
        h1, hl2, wf_hi, wf_lo, bf, out);
}

// Round 12
// 357.430 us; speedup vs baseline: 1.5633x; 1.1131x over previous
//
#include <hip/hip_runtime.h>
#include <hip/hip_fp16.h>
#include <math.h>

// Problem constants (match reference)
#define NN 50000
#define NE 800000
#define DIN 256
#define HH 128      // H1 == H2 == 128
#define DOUT 40
#define NN_PAD 50176   // NN rounded to 256

typedef __attribute__((ext_vector_type(8))) short short8;
typedef __attribute__((ext_vector_type(8))) unsigned short ushort8;
typedef __attribute__((ext_vector_type(4))) float f32x4;

// RNE f32 -> bf16 (as ushort), and back
__device__ __forceinline__ unsigned short f2bf(float f) {
    unsigned int u = __float_as_uint(f);
    unsigned int r = (u + 0x7fffu + ((u >> 16) & 1u)) >> 16;
    return (unsigned short)r;
}
__device__ __forceinline__ float bf2f(unsigned short h) {
    return __uint_as_float(((unsigned int)h) << 16);
}

// ---------------------------------------------------------------------------
// CSR build step 1: in-degree count (self-loop handled as +1 later)
__global__ __launch_bounds__(256) void k_cnt(const int* __restrict__ dst,
                                             int* __restrict__ cnt) {
    int e = blockIdx.x * 256 + threadIdx.x;
    if (e < NE) atomicAdd(&cnt[dst[e]], 1);
}

// CSR build step 2a: per-256-block inclusive scan + block sums; fused dinv
__global__ __launch_bounds__(256) void scan_part(const int* __restrict__ cnt,
                                                 int* __restrict__ incl,
                                                 int* __restrict__ bsum,
                                                 float* __restrict__ dinv) {
    __shared__ int s[256];
    int t = threadIdx.x;
    int id = blockIdx.x * 256 + t;
    int c = cnt[id];                   // cnt padded to NN_PAD, pad = 0
    dinv[id] = rsqrtf((float)c + 1.0f);
    s[t] = c;
    __syncthreads();
    #pragma unroll
    for (int off = 1; off < 256; off <<= 1) {
        int v = (t >= off) ? s[t - off] : 0;
        __syncthreads();
        s[t] += v;
        __syncthreads();
    }
    incl[id] = s[t];
    if (t == 255) bsum[blockIdx.x] = s[255];
}

// CSR build step 2b: exclusive scan of block sums (single block, nb<=256)
__global__ __launch_bounds__(256) void scan_bsum(int* __restrict__ bsum, int nb) {
    __shared__ int s[256];
    int t = threadIdx.x;
    int orig = (t < nb) ? bsum[t] : 0;
    s[t] = orig;
    __syncthreads();
    #pragma unroll
    for (int off = 1; off < 256; off <<= 1) {
        int v = (t >= off) ? s[t - off] : 0;
        __syncthreads();
        s[t] += v;
        __syncthreads();
    }
    if (t < nb) bsum[t] = s[t] - orig;   // exclusive
}

// CSR build step 2c: global exclusive rowptr
__global__ __launch_bounds__(256) void scan_final(const int* __restrict__ incl,
                                                  const int* __restrict__ cnt,
                                                  const int* __restrict__ bsum,
                                                  int* __restrict__ rowptr) {
    int id = blockIdx.x * 256 + threadIdx.x;
    if (id < NN) rowptr[id] = incl[id] - cnt[id] + bsum[id >> 8];
    if (id == 0) rowptr[NN] = NE;
}

// CSR build step 3: fill (src index + precomputed edge norm)
__global__ __launch_bounds__(256) void fill_csr(
    const int* __restrict__ src, const int* __restrict__ dst,
    const float* __restrict__ dinv, const int* __restrict__ rowptr,
    int* __restrict__ cursor, int* __restrict__ csr_src,
    float* __restrict__ csr_norm) {
    int e = blockIdx.x * 256 + threadIdx.x;
    if (e >= NE) return;
    int s = src[e], d = dst[e];
    int pos = rowptr[d] + atomicAdd(&cursor[d], 1);
    csr_src[pos] = s;
    csr_norm[pos] = dinv[s] * dinv[d];
}

// ---------------------------------------------------------------------------
// Weight transpose + bf16 hi/lo split: W[K][128] f32 -> Wt_hi/lo[128][K] bf16.
// blockIdx.y picks one of 4 weights; slot stride 65536 ushorts (hi then lo 32768).
__global__ __launch_bounds__(256) void conv_w(
    const float* __restrict__ W0, const float* __restrict__ W1,
    const float* __restrict__ W2, const float* __restrict__ W3,
    unsigned short* __restrict__ wt) {
    int y = blockIdx.y;
    const float* W = (y == 0) ? W0 : (y == 1) ? W1 : (y == 2) ? W2 : W3;
    int K = (y < 2) ? DIN : HH;
    unsigned short* hi = wt + y * 65536;
    unsigned short* lo = hi + 32768;
    int idx = blockIdx.x * 256 + threadIdx.x;
    if (idx >= K * HH) return;
    int k = idx >> 7, n = idx & 127;
    float f = W[idx];
    unsigned short h = f2bf(f);
    hi[n * K + k] = h;
    lo[n * K + k] = f2bf(f - bf2f(h));
}

// Wf [256][40] f32 -> WfT hi/lo [48][256] bf16 (cols 40..47 zero-padded)
__global__ __launch_bounds__(256) void conv_wf(
    const float* __restrict__ Wf, unsigned short* __restrict__ hi,
    unsigned short* __restrict__ lo) {
    int idx = blockIdx.x * 256 + threadIdx.x;   // 48*256 = 12288
    if (idx >= 48 * 256) return;
    int n = idx >> 8, k = idx & 255;
    float f = (n < DOUT) ? Wf[k * DOUT + n] : 0.f;
    unsigned short h = f2bf(f);
    hi[idx] = h;
    lo[idx] = f2bf(f - bf2f(h));
}

// ---------------------------------------------------------------------------
// Gather aggregation over F16 input rows (halves fabric/cache bytes: the
// gather input is only consumed here and gets bf16-truncated downstream
// anyway; f16 keeps 2^-11 relative accuracy).
// out_f32[d] = sum_{e: dst=d} h16[src]*norm + h16[d]*dinv[d]^2 (+bias)(+relu).
// One node per wave (64 lanes x half2->float2); node index wave-uniform ->
// csr loads become scalar s_loads.
__global__ __launch_bounds__(256) void gather_csr(
    const int* __restrict__ rowptr, const int* __restrict__ csr_src,
    const float* __restrict__ csr_norm, const float* __restrict__ dinv,
    const __half* __restrict__ h, const float* __restrict__ bias,
    float* __restrict__ out, int relu) {
    int node = blockIdx.x * 4 + (threadIdx.x >> 6);   // 12500 blocks x 4 waves
    node = __builtin_amdgcn_readfirstlane(node);      // force SGPR (uniform)
    int lane = threadIdx.x & 63;
    float dd = dinv[node];
    float sl = dd * dd;                               // self-loop norm
    const float2 hv = __half22float2(
        *reinterpret_cast<const __half2*>(&h[(long)node * HH + lane * 2]));
    float2 acc = make_float2(hv.x * sl, hv.y * sl);
    int beg = rowptr[node], end = rowptr[node + 1];
    int i = beg;
    for (; i + 4 <= end; i += 4) {
        int s0 = csr_src[i],     s1 = csr_src[i + 1];
        int s2 = csr_src[i + 2], s3 = csr_src[i + 3];
        float n0 = csr_norm[i],     n1 = csr_norm[i + 1];
        float n2 = csr_norm[i + 2], n3 = csr_norm[i + 3];
        const float2 v0 = __half22float2(
            *reinterpret_cast<const __half2*>(&h[(long)s0 * HH + lane * 2]));
        const float2 v1 = __half22float2(
            *reinterpret_cast<const __half2*>(&h[(long)s1 * HH + lane * 2]));
        const float2 v2 = __half22float2(
            *reinterpret_cast<const __half2*>(&h[(long)s2 * HH + lane * 2]));
        const float2 v3 = __half22float2(
            *reinterpret_cast<const __half2*>(&h[(long)s3 * HH + lane * 2]));
        acc.x += v0.x * n0; acc.y += v0.y * n0;
        acc.x += v1.x * n1; acc.y += v1.y * n1;
        acc.x += v2.x * n2; acc.y += v2.y * n2;
        acc.x += v3.x * n3; acc.y += v3.y * n3;
    }
    for (; i < end; i++) {
        int s0 = csr_src[i];
        float n0 = csr_norm[i];
        const float2 v0 = __half22float2(
            *reinterpret_cast<const __half2*>(&h[(long)s0 * HH + lane * 2]));
        acc.x += v0.x * n0; acc.y += v0.y * n0;
    }
    const float2 bv = *reinterpret_cast<const float2*>(&bias[lane * 2]);
    acc.x += bv.x; acc.y += bv.y;
    if (relu) { acc.x = fmaxf(acc.x, 0.f); acc.y = fmaxf(acc.y, 0.f); }
    *reinterpret_cast<float2*>(&out[(long)node * HH + lane * 2]) = acc;
}

// ---------------------------------------------------------------------------
// Dual-batched MFMA GEMM (bf16x2 split-precision): C[M,128] = A[M,K] @ W[K,128]
// (+bias)(+relu), f32 in; OUTPUT f32 or f16 per problem (outh flag — f16 used
// for gather-input buffers to halve gather bytes).
// acc += Alo*Bhi + Ahi*Blo + Ahi*Bhi  (3x mfma_f32_16x16x32_bf16, f32 acc).
__global__ __launch_bounds__(256) void gemm_mfma_dual(
    const float* __restrict__ A0, const unsigned short* __restrict__ Whi0,
    const unsigned short* __restrict__ Wlo0, void* __restrict__ C0v,
    const float* __restrict__ bias0, int relu0, int outh0,
    const float* __restrict__ A1, const unsigned short* __restrict__ Whi1,
    const unsigned short* __restrict__ Wlo1, void* __restrict__ C1v,
    const float* __restrict__ bias1, int relu1, int outh1,
    int M, int K) {
    __shared__ unsigned short As_hi[128][40];   // [row][k], stride 40 (80B)
    __shared__ unsigned short As_lo[128][40];
    __shared__ unsigned short Bs_hi[128][40];   // [col][k]
    __shared__ unsigned short Bs_lo[128][40];
    const float* A; const unsigned short* Whi; const unsigned short* Wlo;
    void* Cv; const float* bias; int relu, outh;
    if (blockIdx.y == 0) { A = A0; Whi = Whi0; Wlo = Wlo0; Cv = C0v; bias = bias0; relu = relu0; outh = outh0; }
    else                 { A = A1; Whi = Whi1; Wlo = Wlo1; Cv = C1v; bias = bias1; relu = relu1; outh = outh1; }
    const int m0 = blockIdx.x * 128;
    const int tid = threadIdx.x;
    const int w = tid >> 6, l = tid & 63;
    const int lrow = l & 15, lk8 = (l >> 4) * 8;

    f32x4 acc[2][8];
    #pragma unroll
    for (int rb = 0; rb < 2; rb++)
        #pragma unroll
        for (int cb = 0; cb < 8; cb++) acc[rb][cb] = (f32x4){0.f, 0.f, 0.f, 0.f};

    for (int k0 = 0; k0 < K; k0 += 32) {
        // ---- stage A (f32 -> bf16 hi/lo) : 128 rows x 32 k ----
        #pragma unroll
        for (int p = 0; p < 2; p++) {
            int row = (tid >> 2) + p * 64;
            int q = tid & 3;
            int grow = m0 + row;
            float4 a0 = make_float4(0.f, 0.f, 0.f, 0.f);
            float4 a1 = make_float4(0.f, 0.f, 0.f, 0.f);
            if (grow < M) {
                const float* ap = &A[(long)grow * K + k0 + q * 8];
                a0 = *reinterpret_cast<const float4*>(ap);
                a1 = *reinterpret_cast<const float4*>(ap + 4);
            }
            const float v[8] = {a0.x, a0.y, a0.z, a0.w, a1.x, a1.y, a1.z, a1.w};
            ushort8 hi8, lo8;
            #pragma unroll
            for (int j = 0; j < 8; j++) {
                unsigned short h = f2bf(v[j]);
                hi8[j] = h;
                lo8[j] = f2bf(v[j] - bf2f(h));
            }
            *reinterpret_cast<ushort8*>(&As_hi[row][q * 8]) = hi8;
            *reinterpret_cast<ushort8*>(&As_lo[row][q * 8]) = lo8;
        }
        // ---- stage B (pre-split bf16, [col][k]) ----
        #pragma unroll
        for (int p = 0; p < 2; p++) {
            int n = (tid >> 2) + p * 64;
            int q = tid & 3;
            *reinterpret_cast<ushort8*>(&Bs_hi[n][q * 8]) =
                *reinterpret_cast<const ushort8*>(&Whi[(long)n * K + k0 + q * 8]);
            *reinterpret_cast<ushort8*>(&Bs_lo[n][q * 8]) =
                *reinterpret_cast<const ushort8*>(&Wlo[(long)n * K + k0 + q * 8]);
        }
        __syncthreads();
        // ---- MFMA: 2 row-blocks x 8 col-blocks x 3 products ----
        short8 ahi[2], alo[2];
        #pragma unroll
        for (int rb = 0; rb < 2; rb++) {
            int ar = w * 32 + rb * 16 + lrow;
            ahi[rb] = *reinterpret_cast<const short8*>(&As_hi[ar][lk8]);
            alo[rb] = *reinterpret_cast<const short8*>(&As_lo[ar][lk8]);
        }
        #pragma unroll
        for (int cb = 0; cb < 8; cb++) {
            int br = cb * 16 + lrow;
            short8 bhi = *reinterpret_cast<const short8*>(&Bs_hi[br][lk8]);
            short8 blo = *reinterpret_cast<const short8*>(&Bs_lo[br][lk8]);
            #pragma unroll
            for (int rb = 0; rb < 2; rb++) {
                f32x4 t = __builtin_amdgcn_mfma_f32_16x16x32_bf16(alo[rb], bhi, acc[rb][cb], 0, 0, 0);
                t = __builtin_amdgcn_mfma_f32_16x16x32_bf16(ahi[rb], blo, t, 0, 0, 0);
                acc[rb][cb] = __builtin_amdgcn_mfma_f32_16x16x32_bf16(ahi[rb], bhi, t, 0, 0, 0);
            }
        }
        __syncthreads();
    }
    // ---- epilogue: bias + relu + f32 or f16 store ----
    float* Cf = (float*)Cv;
    __half* Ch = (__half*)Cv;
    float bv[8];
    #pragma unroll
    for (int cb = 0; cb < 8; cb++) bv[cb] = bias ? bias[cb * 16 + lrow] : 0.f;
    #pragma unroll
    for (int rb = 0; rb < 2; rb++) {
        #pragma unroll
        for (int j = 0; j < 4; j++) {
            int grow = m0 + w * 32 + rb * 16 + (l >> 4) * 4 + j;
            if (grow < M) {
                #pragma unroll
                for (int cb = 0; cb < 8; cb++) {
                    float o = acc[rb][cb][j] + bv[cb];
                    if (relu) o = fmaxf(o, 0.f);
                    if (outh) Ch[(long)grow * HH + cb * 16 + lrow] = __float2half(o);
                    else      Cf[(long)grow * HH + cb * 16 + lrow] = o;
                }
            }
        }
    }
}

// ---------------------------------------------------------------------------
// Final layer, MFMA, LDS-free: logits = relu(concat(g2,hl2)) @ Wf + bf;
// out = [logits ; softmax(logits)].  A-fragments loaded DIRECTLY from global
// (4 lanes cover each 128B row chunk -> coalesced), concat+relu+bf16-split in
// regs. WfT pre-split [48][256] (cols 40..47 zero). Softmax per row inside the
// 16-lane group that holds its 48 cols (col = cb*16 + (l&15)).
__global__ __launch_bounds__(256) void final_mfma(
    const float* __restrict__ g2, const float* __restrict__ hl2,
    const unsigned short* __restrict__ wfhi, const unsigned short* __restrict__ wflo,
    const float* __restrict__ bf, float* __restrict__ out) {
    const int m0 = blockIdx.x * 128;
    const int tid = threadIdx.x;
    const int w = tid >> 6, l = tid & 63;
    const int lrow = l & 15, lk8 = (l >> 4) * 8;

    f32x4 acc[2][3];
    #pragma unroll
    for (int rb = 0; rb < 2; rb++)
        #pragma unroll
        for (int cb = 0; cb < 3; cb++) acc[rb][cb] = (f32x4){0.f, 0.f, 0.f, 0.f};

    for (int k0 = 0; k0 < 2 * HH; k0 += 32) {
        const float* src = (k0 < HH) ? g2 : hl2;
        const int off = k0 & (HH - 1);
        // B fragments (L2-hot, shared by all blocks)
        short8 bhi[3], blo[3];
        #pragma unroll
        for (int cb = 0; cb < 3; cb++) {
            int br = cb * 16 + lrow;
            bhi[cb] = *reinterpret_cast<const short8*>(&wfhi[br * 256 + k0 + lk8]);
            blo[cb] = *reinterpret_cast<const short8*>(&wflo[br * 256 + k0 + lk8]);
        }
        #pragma unroll
        for (int rb = 0; rb < 2; rb++) {
            int row = m0 + w * 32 + rb * 16 + lrow;
            float4 a0 = make_float4(0.f, 0.f, 0.f, 0.f);
            float4 a1 = make_float4(0.f, 0.f, 0.f, 0.f);
            if (row < NN) {
                const float* ap = &src[(long)row * HH + off + lk8];
                a0 = *reinterpret_cast<const float4*>(ap);
                a1 = *reinterpret_cast<const float4*>(ap + 4);
            }
            const float v[8] = {a0.x, a0.y, a0.z, a0.w, a1.x, a1.y, a1.z, a1.w};
            short8 ahi, alo;
            #pragma unroll
            for (int j = 0; j < 8; j++) {
                float r = fmaxf(v[j], 0.f);           // relu(concat)
                unsigned short h = f2bf(r);
                ahi[j] = (short)h;
                alo[j] = (short)f2bf(r - bf2f(h));
            }
            #pragma unroll
            for (int cb = 0; cb < 3; cb++) {
                f32x4 t = __builtin_amdgcn_mfma_f32_16x16x32_bf16(alo, bhi[cb], acc[rb][cb], 0, 0, 0);
                t = __builtin_amdgcn_mfma_f32_16x16x32_bf16(ahi, blo[cb], t, 0, 0, 0);
                acc[rb][cb] = __builtin_amdgcn_mfma_f32_16x16x32_bf16(ahi, bhi[cb], t, 0, 0, 0);
            }
        }
    }
    // ---- epilogue: bias + softmax within 16-lane group ----
    float bfv[3];
    #pragma unroll
    for (int cb = 0; cb < 3; cb++) {
        int col = cb * 16 + lrow;
        bfv[cb] = (col < DOUT) ? bf[col] : 0.f;
    }
    const bool v2 = (lrow < 8);                       // cb==2 valid only if col<40
    #pragma unroll
    for (int rb = 0; rb < 2; rb++) {
        float lg[3][4];
        #pragma unroll
        for (int cb = 0; cb < 3; cb++)
            #pragma unroll
            for (int j = 0; j < 4; j++) lg[cb][j] = acc[rb][cb][j] + bfv[cb];
        float mx[4], sm[4];
        #pragma unroll
        for (int j = 0; j < 4; j++) {
            mx[j] = fmaxf(lg[0][j], lg[1][j]);
            if (v2) mx[j] = fmaxf(mx[j], lg[2][j]);
        }
        #pragma unroll
        for (int msk = 1; msk <= 8; msk <<= 1)
            #pragma unroll
            for (int j = 0; j < 4; j++) mx[j] = fmaxf(mx[j], __shfl_xor(mx[j], msk));
        float ex[3][4];
        #pragma unroll
        for (int j = 0; j < 4; j++) {
            ex[0][j] = expf(lg[0][j] - mx[j]);
            ex[1][j] = expf(lg[1][j] - mx[j]);
            ex[2][j] = v2 ? expf(lg[2][j] - mx[j]) : 0.f;
            sm[j] = ex[0][j] + ex[1][j] + ex[2][j];
        }
        #pragma unroll
        for (int msk = 1; msk <= 8; msk <<= 1)
            #pragma unroll
            for (int j = 0; j < 4; j++) sm[j] += __shfl_xor(sm[j], msk);
        const int rowb = m0 + w * 32 + rb * 16 + (l >> 4) * 4;
        #pragma unroll
        for (int j = 0; j < 4; j++) {
            int row = rowb + j;
            if (row >= NN) continue;
            float inv = 1.f / sm[j];
            #pragma unroll
            for (int cb = 0; cb < 3; cb++) {
                if (cb == 2 && !v2) continue;
                int col = cb * 16 + lrow;
                out[(long)row * DOUT + col] = lg[cb][j];
                out[(long)NN * DOUT + (long)row * DOUT + col] = ex[cb][j] * inv;
            }
        }
    }
}

// ---------------------------------------------------------------------------
extern "C" void kernel_launch(void* const* d_in, const int* in_sizes, int n_in,
                              void* d_out, int out_size, void* d_ws, size_t ws_size,
                              hipStream_t stream) {
    const float* x   = (const float*)d_in[0];
    const int*   ei  = (const int*)d_in[1];
    const float* Wg1 = (const float*)d_in[2];
    const float* bg1 = (const float*)d_in[3];
    const float* Wg2 = (const float*)d_in[4];
    const float* bg2 = (const float*)d_in[5];
    const float* Wl1 = (const float*)d_in[6];
    const float* bl1 = (const float*)d_in[7];
    const float* Wl2 = (const float*)d_in[8];
    const float* bl2 = (const float*)d_in[9];
    const float* Wf  = (const float*)d_in[10];
    const float* bf  = (const float*)d_in[11];
    float* out = (float*)d_out;

    const int* src = ei;            // edge_index[0]
    const int* dst = ei + NE;       // edge_index[1]

    // Workspace layout. Floats first (16B aligned), then ints, then bf16 wt.
    float* ws   = (float*)d_ws;
    float* dinv = ws;                         // NN_PAD
    float* hg   = dinv + NN_PAD;              // NN*HH slot (gather input, F16 now)
    float* hl   = hg + (long)NN * HH;         // NN*HH   (relu(x@Wl1+bl1), f32)
    float* h1   = hl + (long)NN * HH;         // NN*HH   (gcn agg out, f32)
    float* hl2  = h1 + (long)NN * HH;         // NN*HH
    float* csr_norm = hl2 + (long)NN * HH;    // NE
    int* cnt     = (int*)(csr_norm + NE);     // NN_PAD
    int* incl    = cnt + NN_PAD;              // NN_PAD
    int* bsum    = incl + NN_PAD;             // 256
    int* rowptr  = bsum + 256;                // NN_PAD (uses NN+1)
    int* cursor  = rowptr + NN_PAD;           // NN_PAD
    int* csr_src = cursor + NN_PAD;           // NE
    unsigned short* wt = (unsigned short*)(csr_src + NE);  // 4*65536 ushort
    unsigned short* wg1_hi = wt;              unsigned short* wg1_lo = wt + 32768;
    unsigned short* wl1_hi = wt + 65536;      unsigned short* wl1_lo = wt + 98304;
    unsigned short* wg2_hi = wt + 131072;     unsigned short* wg2_lo = wt + 163840;
    unsigned short* wl2_hi = wt + 196608;     unsigned short* wl2_lo = wt + 229376;
    unsigned short* wf_hi  = wt + 262144;     // 48*256
    unsigned short* wf_lo  = wf_hi + 12288;
    __half* hg16 = (__half*)hg;               // f16 view of gather-input slot

    const int NB = NN_PAD / 256;              // 196

    // ---- CSR build + weight split (per call) ----
    hipMemsetAsync(cnt, 0, NN_PAD * sizeof(int), stream);
    hipMemsetAsync(cursor, 0, NN_PAD * sizeof(int), stream);
    k_cnt<<<(NE + 255) / 256, 256, 0, stream>>>(dst, cnt);
    scan_part<<<NB, 256, 0, stream>>>(cnt, incl, bsum, dinv);
    scan_bsum<<<1, 256, 0, stream>>>(bsum, NB);
    scan_final<<<NB, 256, 0, stream>>>(incl, cnt, bsum, rowptr);
    fill_csr<<<(NE + 255) / 256, 256, 0, stream>>>(src, dst, dinv, rowptr,
                                                   cursor, csr_src, csr_norm);
    conv_w<<<dim3(128, 4), 256, 0, stream>>>(Wg1, Wl1, Wg2, Wl2, wt);
    conv_wf<<<48, 256, 0, stream>>>(Wf, wf_hi, wf_lo);

    // ---- Layer 1 GEMMs (MFMA): hg16 = f16(x@Wg1) ; hl = relu(x@Wl1+bl1) ----
    dim3 g1((NN + 127) / 128, 2);
    gemm_mfma_dual<<<g1, 256, 0, stream>>>(
        x, wg1_hi, wg1_lo, hg16, nullptr, 0, 1,
        x, wl1_hi, wl1_lo, hl, bl1, 1, 0,
        NN, DIN);

    // ---- GCN layer 1 aggregation (f16 in, f32 out; self-loop+bias+relu) ----
    gather_csr<<<NN / 4, 256, 0, stream>>>(
        rowptr, csr_src, csr_norm, dinv, hg16, bg1, h1, 1);

    // ---- Layer 2 GEMMs (MFMA): hg16 = f16(h1@Wg2) ; hl2 = hl@Wl2+bl2 ----
    gemm_mfma_dual<<<g1, 256, 0, stream>>>(
        h1, wg2_hi, wg2_lo, hg16, nullptr, 0, 1,
        hl, wl2_hi, wl2_lo, hl2, bl2, 0, 0,
        NN, HH);

    // ---- GCN layer 2 aggregation (f16 in, f32 out; self-loop + bg2) ----
    gather_csr<<<NN / 4, 256, 0, stream>>>(
        rowptr, csr_src, csr_norm, dinv, hg16, bg2, h1, 0);

    // ---- Final: concat + relu + [256->40] MFMA GEMM + softmax (no LDS) ----
    final_mfma<<<(NN + 127) / 128, 256, 0, stream>>>(
        h1, hl2, wf_hi, wf_lo, bf, out);
}

// Round 13
// 338.034 us; speedup vs baseline: 1.6530x; 1.0574x over previous
//
#include <hip/hip_runtime.h>
#include <hip/hip_fp16.h>
#include <math.h>

// Problem constants (match reference)
#define NN 50000
#define NE 800000
#define DIN 256
#define HH 128      // H1 == H2 == 128
#define DOUT 40
#define NN_PAD 50176   // NN rounded to 256

typedef __attribute__((ext_vector_type(8))) _Float16 half8;
typedef __attribute__((ext_vector_type(8))) unsigned short ushort8;
typedef __attribute__((ext_vector_type(4))) float f32x4;

// ---------------------------------------------------------------------------
// CSR build step 1: in-degree count (self-loop handled as +1 later)
__global__ __launch_bounds__(256) void k_cnt(const int* __restrict__ dst,
                                             int* __restrict__ cnt) {
    int e = blockIdx.x * 256 + threadIdx.x;
    if (e < NE) atomicAdd(&cnt[dst[e]], 1);
}

// CSR build step 2a: per-256-block inclusive scan + block sums; fused dinv
__global__ __launch_bounds__(256) void scan_part(const int* __restrict__ cnt,
                                                 int* __restrict__ incl,
                                                 int* __restrict__ bsum,
                                                 float* __restrict__ dinv) {
    __shared__ int s[256];
    int t = threadIdx.x;
    int id = blockIdx.x * 256 + t;
    int c = cnt[id];                   // cnt padded to NN_PAD, pad = 0
    dinv[id] = rsqrtf((float)c + 1.0f);
    s[t] = c;
    __syncthreads();
    #pragma unroll
    for (int off = 1; off < 256; off <<= 1) {
        int v = (t >= off) ? s[t - off] : 0;
        __syncthreads();
        s[t] += v;
        __syncthreads();
    }
    incl[id] = s[t];
    if (t == 255) bsum[blockIdx.x] = s[255];
}

// CSR build step 2b: exclusive scan of block sums (single block, nb<=256)
__global__ __launch_bounds__(256) void scan_bsum(int* __restrict__ bsum, int nb) {
    __shared__ int s[256];
    int t = threadIdx.x;
    int orig = (t < nb) ? bsum[t] : 0;
    s[t] = orig;
    __syncthreads();
    #pragma unroll
    for (int off = 1; off < 256; off <<= 1) {
        int v = (t >= off) ? s[t - off] : 0;
        __syncthreads();
        s[t] += v;
        __syncthreads();
    }
    if (t < nb) bsum[t] = s[t] - orig;   // exclusive
}

// CSR build step 2c: global exclusive rowptr
__global__ __launch_bounds__(256) void scan_final(const int* __restrict__ incl,
                                                  const int* __restrict__ cnt,
                                                  const int* __restrict__ bsum,
                                                  int* __restrict__ rowptr) {
    int id = blockIdx.x * 256 + threadIdx.x;
    if (id < NN) rowptr[id] = incl[id] - cnt[id] + bsum[id >> 8];
    if (id == 0) rowptr[NN] = NE;
}

// CSR build step 3: fill (src index + precomputed edge norm)
__global__ __launch_bounds__(256) void fill_csr(
    const int* __restrict__ src, const int* __restrict__ dst,
    const float* __restrict__ dinv, const int* __restrict__ rowptr,
    int* __restrict__ cursor, int* __restrict__ csr_src,
    float* __restrict__ csr_norm) {
    int e = blockIdx.x * 256 + threadIdx.x;
    if (e >= NE) return;
    int s = src[e], d = dst[e];
    int pos = rowptr[d] + atomicAdd(&cursor[d], 1);
    csr_src[pos] = s;
    csr_norm[pos] = dinv[s] * dinv[d];
}

// ---------------------------------------------------------------------------
// Weight transpose + f16 convert: W[K][128] f32 -> Wt[128][K] f16.
// blockIdx.y picks one of 4 weights; slot stride 32768 halves.
__global__ __launch_bounds__(256) void conv_w(
    const float* __restrict__ W0, const float* __restrict__ W1,
    const float* __restrict__ W2, const float* __restrict__ W3,
    _Float16* __restrict__ wt) {
    int y = blockIdx.y;
    const float* W = (y == 0) ? W0 : (y == 1) ? W1 : (y == 2) ? W2 : W3;
    int K = (y < 2) ? DIN : HH;
    _Float16* o = wt + y * 32768;
    int idx = blockIdx.x * 256 + threadIdx.x;
    if (idx >= K * HH) return;
    int k = idx >> 7, n = idx & 127;
    o[n * K + k] = (_Float16)W[idx];
}

// Wf [256][40] f32 -> WfT [48][256] f16 (cols 40..47 zero-padded)
__global__ __launch_bounds__(256) void conv_wf(
    const float* __restrict__ Wf, _Float16* __restrict__ o) {
    int idx = blockIdx.x * 256 + threadIdx.x;   // 48*256 = 12288
    if (idx >= 48 * 256) return;
    int n = idx >> 8, k = idx & 255;
    o[idx] = (_Float16)((n < DOUT) ? Wf[k * DOUT + n] : 0.f);
}

// ---------------------------------------------------------------------------
// Gather aggregation over F16 input rows (halves fabric/cache bytes).
// out_f32[d] = sum_{e: dst=d} h16[src]*norm + h16[d]*dinv[d]^2 (+bias)(+relu).
// One node per wave (64 lanes x half2->float2); node index wave-uniform ->
// csr loads become scalar s_loads.
__global__ __launch_bounds__(256) void gather_csr(
    const int* __restrict__ rowptr, const int* __restrict__ csr_src,
    const float* __restrict__ csr_norm, const float* __restrict__ dinv,
    const __half* __restrict__ h, const float* __restrict__ bias,
    float* __restrict__ out, int relu) {
    int node = blockIdx.x * 4 + (threadIdx.x >> 6);   // 12500 blocks x 4 waves
    node = __builtin_amdgcn_readfirstlane(node);      // force SGPR (uniform)
    int lane = threadIdx.x & 63;
    float dd = dinv[node];
    float sl = dd * dd;                               // self-loop norm
    const float2 hv = __half22float2(
        *reinterpret_cast<const __half2*>(&h[(long)node * HH + lane * 2]));
    float2 acc = make_float2(hv.x * sl, hv.y * sl);
    int beg = rowptr[node], end = rowptr[node + 1];
    int i = beg;
    for (; i + 4 <= end; i += 4) {
        int s0 = csr_src[i],     s1 = csr_src[i + 1];
        int s2 = csr_src[i + 2], s3 = csr_src[i + 3];
        float n0 = csr_norm[i],     n1 = csr_norm[i + 1];
        float n2 = csr_norm[i + 2], n3 = csr_norm[i + 3];
        const float2 v0 = __half22float2(
            *reinterpret_cast<const __half2*>(&h[(long)s0 * HH + lane * 2]));
        const float2 v1 = __half22float2(
            *reinterpret_cast<const __half2*>(&h[(long)s1 * HH + lane * 2]));
        const float2 v2 = __half22float2(
            *reinterpret_cast<const __half2*>(&h[(long)s2 * HH + lane * 2]));
        const float2 v3 = __half22float2(
            *reinterpret_cast<const __half2*>(&h[(long)s3 * HH + lane * 2]));
        acc.x += v0.x * n0; acc.y += v0.y * n0;
        acc.x += v1.x * n1; acc.y += v1.y * n1;
        acc.x += v2.x * n2; acc.y += v2.y * n2;
        acc.x += v3.x * n3; acc.y += v3.y * n3;
    }
    for (; i < end; i++) {
        int s0 = csr_src[i];
        float n0 = csr_norm[i];
        const float2 v0 = __half22float2(
            *reinterpret_cast<const __half2*>(&h[(long)s0 * HH + lane * 2]));
        acc.x += v0.x * n0; acc.y += v0.y * n0;
    }
    const float2 bv = *reinterpret_cast<const float2*>(&bias[lane * 2]);
    acc.x += bv.x; acc.y += bv.y;
    if (relu) { acc.x = fmaxf(acc.x, 0.f); acc.y = fmaxf(acc.y, 0.f); }
    *reinterpret_cast<float2*>(&out[(long)node * HH + lane * 2]) = acc;
}

// ---------------------------------------------------------------------------
// Dual-batched F16 MFMA GEMM: C[M,128] = A[M,K] @ W[K,128] (+bias)(+relu).
// f32 in, f16 cast at staging (2^-11 rel err — below the reference's own
// precision floor, validated by the f16 gather rows leaving absmax unchanged).
// Single mfma_f32_16x16x32_f16 per fragment (was 3x bf16 hi/lo): 1/3 the
// matrix work, half the LDS (20.5KB -> 8 blocks/CU ceiling).
// OUTPUT f32 or f16 per problem (outh — f16 for gather-input buffers).
__global__ __launch_bounds__(256) void gemm_mfma_dual(
    const float* __restrict__ A0, const _Float16* __restrict__ W0,
    void* __restrict__ C0v, const float* __restrict__ bias0, int relu0, int outh0,
    const float* __restrict__ A1, const _Float16* __restrict__ W1,
    void* __restrict__ C1v, const float* __restrict__ bias1, int relu1, int outh1,
    int M, int K) {
    __shared__ _Float16 As[128][40];   // [row][k], stride 40 (80B)
    __shared__ _Float16 Bs[128][40];   // [col][k]
    const float* A; const _Float16* W;
    void* Cv; const float* bias; int relu, outh;
    if (blockIdx.y == 0) { A = A0; W = W0; Cv = C0v; bias = bias0; relu = relu0; outh = outh0; }
    else                 { A = A1; W = W1; Cv = C1v; bias = bias1; relu = relu1; outh = outh1; }
    const int m0 = blockIdx.x * 128;
    const int tid = threadIdx.x;
    const int w = tid >> 6, l = tid & 63;
    const int lrow = l & 15, lk8 = (l >> 4) * 8;

    f32x4 acc[2][8];
    #pragma unroll
    for (int rb = 0; rb < 2; rb++)
        #pragma unroll
        for (int cb = 0; cb < 8; cb++) acc[rb][cb] = (f32x4){0.f, 0.f, 0.f, 0.f};

    for (int k0 = 0; k0 < K; k0 += 32) {
        // ---- stage A (f32 -> f16) : 128 rows x 32 k ----
        #pragma unroll
        for (int p = 0; p < 2; p++) {
            int row = (tid >> 2) + p * 64;
            int q = tid & 3;
            int grow = m0 + row;
            float4 a0 = make_float4(0.f, 0.f, 0.f, 0.f);
            float4 a1 = make_float4(0.f, 0.f, 0.f, 0.f);
            if (grow < M) {
                const float* ap = &A[(long)grow * K + k0 + q * 8];
                a0 = *reinterpret_cast<const float4*>(ap);
                a1 = *reinterpret_cast<const float4*>(ap + 4);
            }
            half8 h8;
            h8[0] = (_Float16)a0.x; h8[1] = (_Float16)a0.y;
            h8[2] = (_Float16)a0.z; h8[3] = (_Float16)a0.w;
            h8[4] = (_Float16)a1.x; h8[5] = (_Float16)a1.y;
            h8[6] = (_Float16)a1.z; h8[7] = (_Float16)a1.w;
            *reinterpret_cast<half8*>(&As[row][q * 8]) = h8;
        }
        // ---- stage B (pre-converted f16, [col][k]) ----
        #pragma unroll
        for (int p = 0; p < 2; p++) {
            int n = (tid >> 2) + p * 64;
            int q = tid & 3;
            *reinterpret_cast<half8*>(&Bs[n][q * 8]) =
                *reinterpret_cast<const half8*>(&W[(long)n * K + k0 + q * 8]);
        }
        __syncthreads();
        // ---- MFMA: 2 row-blocks x 8 col-blocks, single f16 product ----
        half8 a16[2];
        #pragma unroll
        for (int rb = 0; rb < 2; rb++) {
            int ar = w * 32 + rb * 16 + lrow;
            a16[rb] = *reinterpret_cast<const half8*>(&As[ar][lk8]);
        }
        #pragma unroll
        for (int cb = 0; cb < 8; cb++) {
            int br = cb * 16 + lrow;
            half8 b16 = *reinterpret_cast<const half8*>(&Bs[br][lk8]);
            #pragma unroll
            for (int rb = 0; rb < 2; rb++)
                acc[rb][cb] = __builtin_amdgcn_mfma_f32_16x16x32_f16(a16[rb], b16, acc[rb][cb], 0, 0, 0);
        }
        __syncthreads();
    }
    // ---- epilogue: bias + relu + f32 or f16 store ----
    float* Cf = (float*)Cv;
    __half* Ch = (__half*)Cv;
    float bv[8];
    #pragma unroll
    for (int cb = 0; cb < 8; cb++) bv[cb] = bias ? bias[cb * 16 + lrow] : 0.f;
    #pragma unroll
    for (int rb = 0; rb < 2; rb++) {
        #pragma unroll
        for (int j = 0; j < 4; j++) {
            int grow = m0 + w * 32 + rb * 16 + (l >> 4) * 4 + j;
            if (grow < M) {
                #pragma unroll
                for (int cb = 0; cb < 8; cb++) {
                    float o = acc[rb][cb][j] + bv[cb];
                    if (relu) o = fmaxf(o, 0.f);
                    if (outh) Ch[(long)grow * HH + cb * 16 + lrow] = __float2half(o);
                    else      Cf[(long)grow * HH + cb * 16 + lrow] = o;
                }
            }
        }
    }
}

// ---------------------------------------------------------------------------
// Final layer, F16 MFMA, LDS-free: logits = relu(concat(g2,hl2)) @ Wf + bf;
// out = [logits ; softmax(logits)].  A-fragments loaded DIRECTLY from global,
// concat+relu+f16-cast in regs. WfT f16 [48][256] (cols 40..47 zero). Softmax
// per row inside the 16-lane group that holds its 48 cols (col=cb*16+(l&15)).
__global__ __launch_bounds__(256) void final_mfma(
    const float* __restrict__ g2, const float* __restrict__ hl2,
    const _Float16* __restrict__ wf16, const float* __restrict__ bf,
    float* __restrict__ out) {
    const int m0 = blockIdx.x * 128;
    const int tid = threadIdx.x;
    const int w = tid >> 6, l = tid & 63;
    const int lrow = l & 15, lk8 = (l >> 4) * 8;

    f32x4 acc[2][3];
    #pragma unroll
    for (int rb = 0; rb < 2; rb++)
        #pragma unroll
        for (int cb = 0; cb < 3; cb++) acc[rb][cb] = (f32x4){0.f, 0.f, 0.f, 0.f};

    for (int k0 = 0; k0 < 2 * HH; k0 += 32) {
        const float* src = (k0 < HH) ? g2 : hl2;
        const int off = k0 & (HH - 1);
        // B fragments (L2-hot, shared by all blocks)
        half8 b16[3];
        #pragma unroll
        for (int cb = 0; cb < 3; cb++) {
            int br = cb * 16 + lrow;
            b16[cb] = *reinterpret_cast<const half8*>(&wf16[br * 256 + k0 + lk8]);
        }
        #pragma unroll
        for (int rb = 0; rb < 2; rb++) {
            int row = m0 + w * 32 + rb * 16 + lrow;
            float4 a0 = make_float4(0.f, 0.f, 0.f, 0.f);
            float4 a1 = make_float4(0.f, 0.f, 0.f, 0.f);
            if (row < NN) {
                const float* ap = &src[(long)row * HH + off + lk8];
                a0 = *reinterpret_cast<const float4*>(ap);
                a1 = *reinterpret_cast<const float4*>(ap + 4);
            }
            half8 a16;
            a16[0] = (_Float16)fmaxf(a0.x, 0.f); a16[1] = (_Float16)fmaxf(a0.y, 0.f);
            a16[2] = (_Float16)fmaxf(a0.z, 0.f); a16[3] = (_Float16)fmaxf(a0.w, 0.f);
            a16[4] = (_Float16)fmaxf(a1.x, 0.f); a16[5] = (_Float16)fmaxf(a1.y, 0.f);
            a16[6] = (_Float16)fmaxf(a1.z, 0.f); a16[7] = (_Float16)fmaxf(a1.w, 0.f);
            #pragma unroll
            for (int cb = 0; cb < 3; cb++)
                acc[rb][cb] = __builtin_amdgcn_mfma_f32_16x16x32_f16(a16, b16[cb], acc[rb][cb], 0, 0, 0);
        }
    }
    // ---- epilogue: bias + softmax within 16-lane group ----
    float bfv[3];
    #pragma unroll
    for (int cb = 0; cb < 3; cb++) {
        int col = cb * 16 + lrow;
        bfv[cb] = (col < DOUT) ? bf[col] : 0.f;
    }
    const bool v2 = (lrow < 8);                       // cb==2 valid only if col<40
    #pragma unroll
    for (int rb = 0; rb < 2; rb++) {
        float lg[3][4];
        #pragma unroll
        for (int cb = 0; cb < 3; cb++)
            #pragma unroll
            for (int j = 0; j < 4; j++) lg[cb][j] = acc[rb][cb][j] + bfv[cb];
        float mx[4], sm[4];
        #pragma unroll
        for (int j = 0; j < 4; j++) {
            mx[j] = fmaxf(lg[0][j], lg[1][j]);
            if (v2) mx[j] = fmaxf(mx[j], lg[2][j]);
        }
        #pragma unroll
        for (int msk = 1; msk <= 8; msk <<= 1)
            #pragma unroll
            for (int j = 0; j < 4; j++) mx[j] = fmaxf(mx[j], __shfl_xor(mx[j], msk));
        float ex[3][4];
        #pragma unroll
        for (int j = 0; j < 4; j++) {
            ex[0][j] = expf(lg[0][j] - mx[j]);
            ex[1][j] = expf(lg[1][j] - mx[j]);
            ex[2][j] = v2 ? expf(lg[2][j] - mx[j]) : 0.f;
            sm[j] = ex[0][j] + ex[1][j] + ex[2][j];
        }
        #pragma unroll
        for (int msk = 1; msk <= 8; msk <<= 1)
            #pragma unroll
            for (int j = 0; j < 4; j++) sm[j] += __shfl_xor(sm[j], msk);
        const int rowb = m0 + w * 32 + rb * 16 + (l >> 4) * 4;
        #pragma unroll
        for (int j = 0; j < 4; j++) {
            int row = rowb + j;
            if (row >= NN) continue;
            float inv = 1.f / sm[j];
            #pragma unroll
            for (int cb = 0; cb < 3; cb++) {
                if (cb == 2 && !v2) continue;
                int col = cb * 16 + lrow;
                out[(long)row * DOUT + col] = lg[cb][j];
                out[(long)NN * DOUT + (long)row * DOUT + col] = ex[cb][j] * inv;
            }
        }
    }
}

// ---------------------------------------------------------------------------
extern "C" void kernel_launch(void* const* d_in, const int* in_sizes, int n_in,
                              void* d_out, int out_size, void* d_ws, size_t ws_size,
                              hipStream_t stream) {
    const float* x   = (const float*)d_in[0];
    const int*   ei  = (const int*)d_in[1];
    const float* Wg1 = (const float*)d_in[2];
    const float* bg1 = (const float*)d_in[3];
    const float* Wg2 = (const float*)d_in[4];
    const float* bg2 = (const float*)d_in[5];
    const float* Wl1 = (const float*)d_in[6];
    const float* bl1 = (const float*)d_in[7];
    const float* Wl2 = (const float*)d_in[8];
    const float* bl2 = (const float*)d_in[9];
    const float* Wf  = (const float*)d_in[10];
    const float* bf  = (const float*)d_in[11];
    float* out = (float*)d_out;

    const int* src = ei;            // edge_index[0]
    const int* dst = ei + NE;       // edge_index[1]

    // Workspace layout. Floats first (16B aligned), then ints, then f16 wt.
    float* ws   = (float*)d_ws;
    float* dinv = ws;                         // NN_PAD
    float* hg   = dinv + NN_PAD;              // NN*HH slot (gather input, F16)
    float* hl   = hg + (long)NN * HH;         // NN*HH   (relu(x@Wl1+bl1), f32)
    float* h1   = hl + (long)NN * HH;         // NN*HH   (gcn agg out, f32)
    float* hl2  = h1 + (long)NN * HH;         // NN*HH
    float* csr_norm = hl2 + (long)NN * HH;    // NE
    int* cnt     = (int*)(csr_norm + NE);     // NN_PAD
    int* incl    = cnt + NN_PAD;              // NN_PAD
    int* bsum    = incl + NN_PAD;             // 256
    int* rowptr  = bsum + 256;                // NN_PAD (uses NN+1)
    int* cursor  = rowptr + NN_PAD;           // NN_PAD
    int* csr_src = cursor + NN_PAD;           // NE
    _Float16* wt = (_Float16*)(csr_src + NE); // 4*32768 + 12288 halves
    _Float16* wg1_16 = wt;                    // [128][256]
    _Float16* wl1_16 = wt + 32768;            // [128][256]
    _Float16* wg2_16 = wt + 65536;            // [128][128]
    _Float16* wl2_16 = wt + 98304;            // [128][128]
    _Float16* wf_16  = wt + 131072;           // [48][256]
    __half* hg16 = (__half*)hg;               // f16 view of gather-input slot

    const int NB = NN_PAD / 256;              // 196

    // ---- CSR build + weight convert (per call) ----
    hipMemsetAsync(cnt, 0, NN_PAD * sizeof(int), stream);
    hipMemsetAsync(cursor, 0, NN_PAD * sizeof(int), stream);
    k_cnt<<<(NE + 255) / 256, 256, 0, stream>>>(dst, cnt);
    scan_part<<<NB, 256, 0, stream>>>(cnt, incl, bsum, dinv);
    scan_bsum<<<1, 256, 0, stream>>>(bsum, NB);
    scan_final<<<NB, 256, 0, stream>>>(incl, cnt, bsum, rowptr);
    fill_csr<<<(NE + 255) / 256, 256, 0, stream>>>(src, dst, dinv, rowptr,
                                                   cursor, csr_src, csr_norm);
    conv_w<<<dim3(128, 4), 256, 0, stream>>>(Wg1, Wl1, Wg2, Wl2, wt);
    conv_wf<<<48, 256, 0, stream>>>(Wf, wf_16);

    // ---- Layer 1 GEMMs (f16 MFMA): hg16 = f16(x@Wg1) ; hl = relu(x@Wl1+bl1)
    dim3 g1((NN + 127) / 128, 2);
    gemm_mfma_dual<<<g1, 256, 0, stream>>>(
        x, wg1_16, hg16, nullptr, 0, 1,
        x, wl1_16, hl, bl1, 1, 0,
        NN, DIN);

    // ---- GCN layer 1 aggregation (f16 in, f32 out; self-loop+bias+relu) ----
    gather_csr<<<NN / 4, 256, 0, stream>>>(
        rowptr, csr_src, csr_norm, dinv, hg16, bg1, h1, 1);

    // ---- Layer 2 GEMMs (f16 MFMA): hg16 = f16(h1@Wg2) ; hl2 = hl@Wl2+bl2 ----
    gemm_mfma_dual<<<g1, 256, 0, stream>>>(
        h1, wg2_16, hg16, nullptr, 0, 1,
        hl, wl2_16, hl2, bl2, 0, 0,
        NN, HH);

    // ---- GCN layer 2 aggregation (f16 in, f32 out; self-loop + bg2) ----
    gather_csr<<<NN / 4, 256, 0, stream>>>(
        rowptr, csr_src, csr_norm, dinv, hg16, bg2, h1, 0);

    // ---- Final: concat + relu + [256->40] f16 MFMA GEMM + softmax ----
    final_mfma<<<(NN + 127) / 128, 256, 0, stream>>>(
        h1, hl2, wf_16, bf, out);
}